// Round 15
// baseline (675.151 us; speedup 1.0000x reference)
//
#include <hip/hip_runtime.h>
#include <math.h>

#define NB 2
#define NS 1024
#define NH 8
#define NDK 64
#define ND 512
#define NDFF 2048
#define NV 32000
#define NL 6
#define MROWS (NB * NS)
#define QKVLD (3 * ND)   // 1536

using bf16_t = __bf16;
using bf16x4 = __attribute__((ext_vector_type(4))) __bf16;
using bf16x8 = __attribute__((ext_vector_type(8))) __bf16;
using f32x4  = __attribute__((ext_vector_type(4))) float;

__device__ __forceinline__ void gload_lds16(const bf16_t* g, bf16_t* l) {
  __builtin_amdgcn_global_load_lds(
      (const __attribute__((address_space(1))) void*)g,
      (__attribute__((address_space(3))) void*)l, 16, 0, 0);
}

__device__ __forceinline__ float gelu_exact(float v) {
  return 0.5f * v * (1.0f + erff(v * 0.7071067811865476f));
}

// ---------------------------------------------------------------- prep: all weight transposes + embed
__global__ __launch_bounds__(256)
void prep_kernel(const int* __restrict__ tokens, const float* __restrict__ emb,
                 const float* __restrict__ Wq, const float* __restrict__ Wk,
                 const float* __restrict__ Wv, const float* __restrict__ Wo,
                 const float* __restrict__ W1, const float* __restrict__ W2,
                 const float* __restrict__ Wout,
                 bf16_t* __restrict__ WqkvT, bf16_t* __restrict__ WoT,
                 bf16_t* __restrict__ W1T, bf16_t* __restrict__ W2T,
                 bf16_t* __restrict__ WoutT,
                 float* __restrict__ x, bf16_t* __restrict__ xb) {
  __shared__ bf16_t T[64][72];
  const int id = blockIdx.x;
  const int tid = threadIdx.x;

  if (id >= 8608) {                       // ---- embed
    const int row = id - 8608;            // b*NS + s
    const int s = row & (NS - 1);
    const int tok = tokens[row];
    const float SQRTD = 22.627416997969522f;
    const float C = -9.210340371976184f / (float)ND;
#pragma unroll
    for (int i = 0; i < 2; ++i) {
      const int d = tid + i * 256;
      const int pair = d >> 1;
      const float div = expf((float)(2 * pair) * C);
      const float ang = (float)s * div;
      const float pe = (d & 1) ? cosf(ang) : sinf(ang);
      const float v = emb[(size_t)tok * ND + d] * SQRTD + pe;
      x[(size_t)row * ND + d] = v;
      xb[(size_t)row * ND + d] = (bf16_t)v;
    }
    return;
  }

  const float* src; bf16_t* dst; int K, N, n0, k0;
  if (id < 1536) {                        // Wq/Wk/Wv/Wo, 512x512 each
    const int z = id >> 6, t = id & 63;
    const int mat = z / 6, layer = z % 6;
    src = ((mat == 0) ? Wq : (mat == 1) ? Wk : (mat == 2) ? Wv : Wo) + (size_t)layer * ND * ND;
    dst = (mat < 3) ? (WqkvT + (size_t)layer * QKVLD * ND + (size_t)mat * ND * ND)
                    : (WoT + (size_t)layer * ND * ND);
    K = ND; N = ND; n0 = (t & 7) * 64; k0 = (t >> 3) * 64;
  } else if (id < 3072) {                 // W1: [512][2048]
    const int idx = id - 1536, layer = idx >> 8, t = idx & 255;
    src = W1 + (size_t)layer * ND * NDFF; dst = W1T + (size_t)layer * NDFF * ND;
    K = ND; N = NDFF; n0 = (t & 31) * 64; k0 = (t >> 5) * 64;
  } else if (id < 4608) {                 // W2: [2048][512]
    const int idx = id - 3072, layer = idx >> 8, t = idx & 255;
    src = W2 + (size_t)layer * NDFF * ND; dst = W2T + (size_t)layer * ND * NDFF;
    K = NDFF; N = ND; n0 = (t & 7) * 64; k0 = (t >> 3) * 64;
  } else {                                // Wout: [512][32000]
    const int t = id - 4608;
    src = Wout; dst = WoutT;
    K = ND; N = NV; n0 = (t % 500) * 64; k0 = (t / 500) * 64;
  }

#pragma unroll
  for (int it = 0; it < 4; ++it) {
    const int k = (tid >> 4) + it * 16;
    const int c = (tid & 15) * 4;
    const float4 v = *(const float4*)&src[(size_t)(k0 + k) * N + n0 + c];
    T[c + 0][k] = (bf16_t)v.x;
    T[c + 1][k] = (bf16_t)v.y;
    T[c + 2][k] = (bf16_t)v.z;
    T[c + 3][k] = (bf16_t)v.w;
  }
  __syncthreads();
  const int n = tid >> 2, kk = (tid & 3) * 16;
  bf16x8 a = *(const bf16x8*)&T[n][kk];
  bf16x8 b2v = *(const bf16x8*)&T[n][kk + 8];
  *(bf16x8*)&dst[(size_t)(n0 + n) * K + k0 + kk] = a;
  *(bf16x8*)&dst[(size_t)(n0 + n) * K + k0 + kk + 8] = b2v;
}

// ---------------------------------------------------------------- residual add (two partials) + LayerNorm (+ optional second LN)
__global__ __launch_bounds__(256)
void add_ln_kernel(float* __restrict__ x, const float* __restrict__ y0,
                   const float* __restrict__ y1,
                   const float* __restrict__ g, const float* __restrict__ bb,
                   const float* __restrict__ g2, const float* __restrict__ bb2,
                   bf16_t* __restrict__ xb) {
  const int row = blockIdx.x, tid = threadIdx.x;
  const size_t base = (size_t)row * ND;
  float v0 = x[base + tid], v1 = x[base + tid + 256];
  if (y0) { v0 += y0[base + tid]; v1 += y0[base + tid + 256]; }
  if (y1) { v0 += y1[base + tid]; v1 += y1[base + tid + 256]; }
  __shared__ float red[256];
  red[tid] = v0 + v1; __syncthreads();
  for (int o = 128; o > 0; o >>= 1) {
    if (tid < o) red[tid] += red[tid + o];
    __syncthreads();
  }
  const float mean = red[0] * (1.f / (float)ND);
  __syncthreads();
  const float d0 = v0 - mean, d1 = v1 - mean;
  red[tid] = d0 * d0 + d1 * d1; __syncthreads();
  for (int o = 128; o > 0; o >>= 1) {
    if (tid < o) red[tid] += red[tid + o];
    __syncthreads();
  }
  const float inv = 1.f / sqrtf(red[0] * (1.f / (float)ND) + 1e-5f);
  float o0 = d0 * inv * g[tid]       + bb[tid];
  float o1 = d1 * inv * g[tid + 256] + bb[tid + 256];

  if (g2) {       // fused second LayerNorm (final lnf)
    __syncthreads();
    red[tid] = o0 + o1; __syncthreads();
    for (int o = 128; o > 0; o >>= 1) {
      if (tid < o) red[tid] += red[tid + o];
      __syncthreads();
    }
    const float mean2 = red[0] * (1.f / (float)ND);
    __syncthreads();
    const float e0 = o0 - mean2, e1 = o1 - mean2;
    red[tid] = e0 * e0 + e1 * e1; __syncthreads();
    for (int o = 128; o > 0; o >>= 1) {
      if (tid < o) red[tid] += red[tid + o];
      __syncthreads();
    }
    const float inv2 = 1.f / sqrtf(red[0] * (1.f / (float)ND) + 1e-5f);
    o0 = e0 * inv2 * g2[tid]       + bb2[tid];
    o1 = e1 * inv2 * g2[tid + 256] + bb2[tid + 256];
  } else {
    x[base + tid] = o0;
    x[base + tid + 256] = o1;
  }
  xb[base + tid] = (bf16_t)o0; xb[base + tid + 256] = (bf16_t)o1;
}

// ---------------------------------------------------------------- 128x128 GEMM, BK=64 (logits), XCD swizzle
template <int ACT, int OUTBF>
__global__ __launch_bounds__(256)
void gemm_bt(const bf16_t* __restrict__ A, const bf16_t* __restrict__ Wt,
             const float* __restrict__ B0,
             void* __restrict__ Cout, int N, int K, int lda, int ldc) {
  __shared__ bf16_t As[128 * 64];
  __shared__ bf16_t Bs[128 * 64];
  const int tid = threadIdx.x, lane = tid & 63, w = tid >> 6;
  const int wm = w >> 1, wn = w & 1;
  const int lcol = lane & 15, hi = lane >> 4;

  // bijective XCD swizzle (m204)
  const int nwg = gridDim.x * gridDim.y;
  const int flat = blockIdx.y * gridDim.x + blockIdx.x;
  const int q = nwg >> 3, r = nwg & 7;
  const int xcd = flat & 7, idx = flat >> 3;
  const int nf = (xcd < r ? xcd * (q + 1) : r * (q + 1) + (xcd - r) * q) + idx;
  const int m0 = (nf % gridDim.x) * 128, n0 = (nf / gridDim.x) * 128;

  const int sr8 = lane >> 3;        // 0..7
  const int sslot = lane & 7;       // 16B slot 0..7

  f32x4 acc[4][4] = {};

  for (int k0 = 0; k0 < K; k0 += 64) {
#pragma unroll
    for (int t = 0; t < 2; ++t) {
#pragma unroll
      for (int c = 0; c < 2; ++c) {
        const int rbase = t * 64 + w * 16 + c * 8;     // wave-uniform
        const int row = rbase + sr8;
        const int ks = sslot ^ (row & 7);
        gload_lds16(&A[(size_t)(m0 + row) * lda + k0 + ks * 8], &As[rbase * 64]);
        gload_lds16(&Wt[(size_t)(n0 + row) * K + k0 + ks * 8], &Bs[rbase * 64]);
      }
    }
    __syncthreads();

#pragma unroll
    for (int kk = 0; kk < 2; ++kk) {
      bf16x8 af[4], bf[4];
#pragma unroll
      for (int m = 0; m < 4; ++m) {
        const int rr = wm * 64 + m * 16 + lcol;
        af[m] = *(const bf16x8*)&As[rr * 64 + (((kk * 4 + hi) ^ (rr & 7)) * 8)];
      }
#pragma unroll
      for (int n = 0; n < 4; ++n) {
        const int rr = wn * 64 + n * 16 + lcol;
        bf[n] = *(const bf16x8*)&Bs[rr * 64 + (((kk * 4 + hi) ^ (rr & 7)) * 8)];
      }
#pragma unroll
      for (int m = 0; m < 4; ++m)
#pragma unroll
        for (int n = 0; n < 4; ++n)
          acc[m][n] = __builtin_amdgcn_mfma_f32_16x16x32_bf16(bf[n], af[m], acc[m][n], 0, 0, 0);
    }
    __syncthreads();
  }

#pragma unroll
  for (int m = 0; m < 4; ++m) {
    const int row = m0 + wm * 64 + m * 16 + lcol;
#pragma unroll
    for (int n = 0; n < 4; ++n) {
      const int col = n0 + wn * 64 + n * 16 + hi * 4;
      const f32x4 bv = *(const f32x4*)&B0[col];
      f32x4 v;
#pragma unroll
      for (int i = 0; i < 4; ++i) {
        float t = acc[m][n][i] + bv[i];
        if (ACT == 1) t = gelu_exact(t);
        v[i] = t;
      }
      if (OUTBF) {
        bf16x4 o;
#pragma unroll
        for (int i = 0; i < 4; ++i) o[i] = (bf16_t)v[i];
        *(bf16x4*)&((bf16_t*)Cout)[(size_t)row * ldc + col] = o;
      } else {
        __builtin_nontemporal_store(v, (f32x4*)&((float*)Cout)[(size_t)row * ldc + col]);
      }
    }
  }
}

// ---------------------------------------------------------------- 64x64 GEMM, BK=128, 3-way bias (QKV), bf16 out
__global__ __launch_bounds__(256)
void gemm_qkv64(const bf16_t* __restrict__ A, const bf16_t* __restrict__ Wt,
                const float* __restrict__ B0, const float* __restrict__ B1,
                const float* __restrict__ B2,
                bf16_t* __restrict__ Cout, int K, int lda, int ldc) {
  __shared__ bf16_t As[64 * 128];   // 16KB each, row stride 256B, 16 slots
  __shared__ bf16_t Bs[64 * 128];
  const int tid = threadIdx.x, lane = tid & 63, w = tid >> 6;
  const int wm = w >> 1, wn = w & 1;
  const int lcol = lane & 15, hi = lane >> 4;
  const int m0 = blockIdx.x * 64, n0 = blockIdx.y * 64;
  const int sr4 = lane >> 4, sslot = lane & 15;

  f32x4 acc[2][2] = {};

  for (int k0 = 0; k0 < K; k0 += 128) {
#pragma unroll
    for (int c = 0; c < 4; ++c) {
      const int rbase = w * 16 + c * 4;                // wave-uniform
      const int row = rbase + sr4;
      const int ks = sslot ^ (row & 15);
      gload_lds16(&A[(size_t)(m0 + row) * lda + k0 + ks * 8], &As[rbase * 128]);
      gload_lds16(&Wt[(size_t)(n0 + row) * K + k0 + ks * 8], &Bs[rbase * 128]);
    }
    __syncthreads();

#pragma unroll
    for (int kk = 0; kk < 4; ++kk) {
      bf16x8 af[2], bf[2];
#pragma unroll
      for (int m = 0; m < 2; ++m) {
        const int rr = wm * 32 + m * 16 + lcol;
        af[m] = *(const bf16x8*)&As[rr * 128 + (((kk * 4 + hi) ^ (rr & 15)) * 8)];
      }
#pragma unroll
      for (int n = 0; n < 2; ++n) {
        const int rr = wn * 32 + n * 16 + lcol;
        bf[n] = *(const bf16x8*)&Bs[rr * 128 + (((kk * 4 + hi) ^ (rr & 15)) * 8)];
      }
#pragma unroll
      for (int m = 0; m < 2; ++m)
#pragma unroll
        for (int n = 0; n < 2; ++n)
          acc[m][n] = __builtin_amdgcn_mfma_f32_16x16x32_bf16(bf[n], af[m], acc[m][n], 0, 0, 0);
    }
    __syncthreads();
  }

#pragma unroll
  for (int m = 0; m < 2; ++m) {
    const int row = m0 + wm * 32 + m * 16 + lcol;
#pragma unroll
    for (int n = 0; n < 2; ++n) {
      const int col = n0 + wn * 32 + n * 16 + hi * 4;
      const int sel = col >> 9;
      const float* Bp = (sel == 0) ? B0 : (sel == 1) ? B1 : B2;
      const f32x4 bv = *(const f32x4*)&Bp[col & 511];
      bf16x4 o;
#pragma unroll
      for (int i = 0; i < 4; ++i) o[i] = (bf16_t)(acc[m][n][i] + bv[i]);
      *(bf16x4*)&Cout[(size_t)row * ldc + col] = o;
    }
  }
}

// ---------------------------------------------------------------- 64x64 GEMM, BK=128, single bias, optional split-K
// Wt col index = (k & kmask) so a wide-K A (concatenated partials) can share one [N][512] W.
template <int ACT, int OUTBF>
__global__ __launch_bounds__(256)
void gemm64(const bf16_t* __restrict__ A, const bf16_t* __restrict__ Wt,
            const float* __restrict__ bias,
            void* __restrict__ Cout, int K, int lda, int ldw, int kmask,
            int ldc, size_t zstride) {
  __shared__ bf16_t As[64 * 128];
  __shared__ bf16_t Bs[64 * 128];
  const int tid = threadIdx.x, lane = tid & 63, w = tid >> 6;
  const int wm = w >> 1, wn = w & 1;
  const int lcol = lane & 15, hi = lane >> 4;
  const int m0 = blockIdx.x * 64, n0 = blockIdx.y * 64;
  const int sr4 = lane >> 4, sslot = lane & 15;
  const int kc = K / gridDim.z;
  const int kbeg = blockIdx.z * kc;

  f32x4 acc[2][2] = {};

  for (int k0 = kbeg; k0 < kbeg + kc; k0 += 128) {
#pragma unroll
    for (int c = 0; c < 4; ++c) {
      const int rbase = w * 16 + c * 4;
      const int row = rbase + sr4;
      const int ks = sslot ^ (row & 15);
      gload_lds16(&A[(size_t)(m0 + row) * lda + k0 + ks * 8], &As[rbase * 128]);
      gload_lds16(&Wt[(size_t)(n0 + row) * ldw + ((k0 & kmask) + ks * 8)], &Bs[rbase * 128]);
    }
    __syncthreads();

#pragma unroll
    for (int kk = 0; kk < 4; ++kk) {
      bf16x8 af[2], bf[2];
#pragma unroll
      for (int m = 0; m < 2; ++m) {
        const int rr = wm * 32 + m * 16 + lcol;
        af[m] = *(const bf16x8*)&As[rr * 128 + (((kk * 4 + hi) ^ (rr & 15)) * 8)];
      }
#pragma unroll
      for (int n = 0; n < 2; ++n) {
        const int rr = wn * 32 + n * 16 + lcol;
        bf[n] = *(const bf16x8*)&Bs[rr * 128 + (((kk * 4 + hi) ^ (rr & 15)) * 8)];
      }
#pragma unroll
      for (int m = 0; m < 2; ++m)
#pragma unroll
        for (int n = 0; n < 2; ++n)
          acc[m][n] = __builtin_amdgcn_mfma_f32_16x16x32_bf16(bf[n], af[m], acc[m][n], 0, 0, 0);
    }
    __syncthreads();
  }

#pragma unroll
  for (int m = 0; m < 2; ++m) {
    const int row = m0 + wm * 32 + m * 16 + lcol;
#pragma unroll
    for (int n = 0; n < 2; ++n) {
      const int col = n0 + wn * 32 + n * 16 + hi * 4;
      f32x4 bv = {0.f, 0.f, 0.f, 0.f};
      if (blockIdx.z == 0) bv = *(const f32x4*)&bias[col];
      f32x4 v;
#pragma unroll
      for (int i = 0; i < 4; ++i) {
        float t = acc[m][n][i] + bv[i];
        if (ACT == 1) t = gelu_exact(t);
        v[i] = t;
      }
      if (OUTBF) {
        bf16x4 o;
#pragma unroll
        for (int i = 0; i < 4; ++i) o[i] = (bf16_t)v[i];
        *(bf16x4*)&((bf16_t*)Cout)[(size_t)row * ldc + col] = o;
      } else {
        *(f32x4*)&((float*)Cout)[blockIdx.z * zstride + (size_t)row * ldc + col] = v;
      }
    }
  }
}

// ---------------------------------------------------------------- attention stats: partial (m,s) per t-quarter
// grid (16, NH, NB*4); z -> b = z>>2, quarter = z&3. Tiles tt = quar, quar+4, ...
// Q staged into Ks rows 0-63 (overwritten by first K tile).
__global__ __launch_bounds__(256)
void attn_stats(const bf16_t* __restrict__ qkv,
                float* __restrict__ marr, float* __restrict__ sarr,
                float* __restrict__ probs) {
  const int qt = 15 - blockIdx.x;            // heavy blocks first
  const int h = blockIdx.y;
  const int b = blockIdx.z >> 2, quar = blockIdx.z & 3;
  const int q0 = qt * 64;
  const int NTT = (q0 >> 7) + 1;
  const int qmax = q0 + 63;
  const int tid = threadIdx.x, lane = tid & 63, wq = tid >> 6;
  const int lcol = lane & 15, hi = lane >> 4;

  __shared__ bf16_t Ks[128][72];

  // zero-fill probs tail (quarter 0 only) — overlaps compute of other quarters
  if (quar == 0) {
    const int z0 = NTT * 128;
    const int nz = (NS - z0) >> 2;
    if (nz > 0) {
      const f32x4 zf = {0.f, 0.f, 0.f, 0.f};
      for (int idx = tid; idx < 64 * nz; idx += 256) {
        const int r = idx / nz, c = (idx - r * nz) * 4;
        __builtin_nontemporal_store(zf,
            (f32x4*)&probs[(((size_t)b * NH + h) * NS + q0 + r) * NS + z0 + c]);
      }
    }
  }

  // stage Q into Ks rows 0..63 (transient)
  {
    const int r = tid >> 2, c = (tid & 3) * 16;
    const bf16_t* src = &qkv[((size_t)(b * NS + q0 + r)) * QKVLD + h * NDK + c];
    *(bf16x8*)&Ks[r][c]     = *(const bf16x8*)&src[0];
    *(bf16x8*)&Ks[r][c + 8] = *(const bf16x8*)&src[8];
  }
  __syncthreads();
  const bf16x8 qf0 = *(const bf16x8*)&Ks[wq * 16 + lcol][hi * 8];
  const bf16x8 qf1 = *(const bf16x8*)&Ks[wq * 16 + lcol][32 + hi * 8];
  __syncthreads();    // all waves hold Q in regs before Ks is overwritten
  const int qrow = q0 + wq * 16 + lcol;
  const float scale = 0.125f;

  float m_run = -1e30f, s_run = 0.f;

  for (int tt = quar; tt < NTT; tt += 4) {
    const int t0 = tt * 128;
    const int fmax = min(8, ((qmax - t0) >> 4) + 1);
    {
      const int r = tid >> 1, cb = (tid & 1) * 32;
      const bf16_t* src = &qkv[((size_t)(b * NS + t0 + r)) * QKVLD + ND + h * NDK + cb];
#pragma unroll
      for (int j = 0; j < 4; ++j)
        *(bf16x8*)&Ks[r][cb + j * 8] = *(const bf16x8*)&src[j * 8];
    }
    __syncthreads();

    float tmax = -1e30f;
    f32x4 sc[8];
#pragma unroll
    for (int f = 0; f < 8; ++f) {
      if (f >= fmax) break;
      f32x4 s4 = {};
      const bf16x8 ka0 = *(const bf16x8*)&Ks[f * 16 + lcol][hi * 8];
      const bf16x8 ka1 = *(const bf16x8*)&Ks[f * 16 + lcol][32 + hi * 8];
      s4 = __builtin_amdgcn_mfma_f32_16x16x32_bf16(ka0, qf0, s4, 0, 0, 0);
      s4 = __builtin_amdgcn_mfma_f32_16x16x32_bf16(ka1, qf1, s4, 0, 0, 0);
#pragma unroll
      for (int i = 0; i < 4; ++i) {
        const int t = t0 + f * 16 + hi * 4 + i;
        const float v = (t <= qrow) ? s4[i] * scale : -1e30f;
        s4[i] = v;
        tmax = fmaxf(tmax, v);
      }
      sc[f] = s4;
    }
    tmax = fmaxf(tmax, __shfl_xor(tmax, 16));
    tmax = fmaxf(tmax, __shfl_xor(tmax, 32));
    const float m_new = fmaxf(m_run, tmax);
    float sum = 0.f;
#pragma unroll
    for (int f = 0; f < 8; ++f) {
      if (f >= fmax) break;
#pragma unroll
      for (int i = 0; i < 4; ++i) sum += __expf(sc[f][i] - m_new);
    }
    sum += __shfl_xor(sum, 16);
    sum += __shfl_xor(sum, 32);
    s_run = s_run * __expf(m_run - m_new) + sum;
    m_run = m_new;
    __syncthreads();
  }

  if (hi == 0) {
    const size_t idx = (((size_t)quar * NB + b) * NH + h) * NS + qrow;
    marr[idx] = m_run;
    sarr[idx] = s_run;
  }
}

// ---------------------------------------------------------------- attention probs+PV, t-quarter split, merged stats
// ctxcat: [M][2048] bf16, quarter q writes cols [q*512 + head*64 .. +64)
__global__ __launch_bounds__(256)
void attn_pv(const bf16_t* __restrict__ qkv,
             const float* __restrict__ marr, const float* __restrict__ sarr,
             float* __restrict__ probs, bf16_t* __restrict__ ctxcat) {
  const int qt = 15 - blockIdx.x;
  const int h = blockIdx.y;
  const int b = blockIdx.z >> 2, quar = blockIdx.z & 3;
  const int q0 = qt * 64;
  const int NTT = (q0 >> 7) + 1;
  const int qmax = q0 + 63;
  const int tid = threadIdx.x, lane = tid & 63, wq = tid >> 6;
  const int lcol = lane & 15, hi = lane >> 4;

  __shared__ bf16_t Ks[128][72];
  __shared__ bf16_t Vs[64][132];
  __shared__ bf16_t Ps[64][132];
  bf16_t (*Qs)[72] = (bf16_t(*)[72])&Vs[0][0];   // transient overlay (9.2KB <= 16.9KB)

  // stage Q into the Vs region (transient)
  {
    const int r = tid >> 2, c = (tid & 3) * 16;
    const bf16_t* src = &qkv[((size_t)(b * NS + q0 + r)) * QKVLD + h * NDK + c];
    *(bf16x8*)&Qs[r][c]     = *(const bf16x8*)&src[0];
    *(bf16x8*)&Qs[r][c + 8] = *(const bf16x8*)&src[8];
  }
  __syncthreads();
  const bf16x8 qf0 = *(const bf16x8*)&Qs[wq * 16 + lcol][hi * 8];
  const bf16x8 qf1 = *(const bf16x8*)&Qs[wq * 16 + lcol][32 + hi * 8];
  __syncthreads();    // all waves hold Q in regs before Vs is overwritten
  const int qrow = q0 + wq * 16 + lcol;
  const float scale = 0.125f;

  // merge the four partial stats
  float mq0, mq1, mq2, mq3, sq0, sq1, sq2, sq3;
  {
    const size_t strideq = (size_t)NB * NH * NS;
    const size_t i0 = (((size_t)b * NH + h) * NS) + qrow;
    mq0 = marr[i0]; mq1 = marr[i0 + strideq]; mq2 = marr[i0 + 2 * strideq]; mq3 = marr[i0 + 3 * strideq];
    sq0 = sarr[i0]; sq1 = sarr[i0 + strideq]; sq2 = sarr[i0 + 2 * strideq]; sq3 = sarr[i0 + 3 * strideq];
  }
  const float m_fin = fmaxf(fmaxf(mq0, mq1), fmaxf(mq2, mq3));
  const float s_fin = sq0 * __expf(mq0 - m_fin) + sq1 * __expf(mq1 - m_fin) +
                      sq2 * __expf(mq2 - m_fin) + sq3 * __expf(mq3 - m_fin);
  const float inv = 1.f / s_fin;

  f32x4 cacc[4] = {};
  const size_t prow = (((size_t)b * NH + h) * NS + qrow) * NS;
  for (int tt = quar; tt < NTT; tt += 4) {
    const int t0 = tt * 128;
    const int fmax = min(8, ((qmax - t0) >> 4) + 1);
    {
      const int r = tid >> 1, cb = (tid & 1) * 32;
      const bf16_t* src = &qkv[((size_t)(b * NS + t0 + r)) * QKVLD + ND + h * NDK + cb];
#pragma unroll
      for (int j = 0; j < 4; ++j)
        *(bf16x8*)&Ks[r][cb + j * 8] = *(const bf16x8*)&src[j * 8];
    }
    {
      // V: register 4x4 transpose -> vectorized b64 LDS stores
#pragma unroll
      for (int it = 0; it < 2; ++it) {
        const int t4 = (tid >> 4) * 4 + it * 64;
        const int dk4 = (tid & 15) * 4;
        bf16x4 rr[4];
#pragma unroll
        for (int i = 0; i < 4; ++i)
          rr[i] = *(const bf16x4*)&qkv[((size_t)(b * NS + t0 + t4 + i)) * QKVLD + 2 * ND + h * NDK + dk4];
#pragma unroll
        for (int j = 0; j < 4; ++j) {
          bf16x4 c;
#pragma unroll
          for (int i = 0; i < 4; ++i) c[i] = rr[i][j];
          *(bf16x4*)&Vs[dk4 + j][t4] = c;
        }
      }
    }
    __syncthreads();

    const f32x4 zf = {0.f, 0.f, 0.f, 0.f};
    const bf16x4 zb = {(bf16_t)0.f, (bf16_t)0.f, (bf16_t)0.f, (bf16_t)0.f};
#pragma unroll
    for (int f = 0; f < 8; ++f) {
      if (f < fmax) {
        f32x4 s4 = {};
        const bf16x8 ka0 = *(const bf16x8*)&Ks[f * 16 + lcol][hi * 8];
        const bf16x8 ka1 = *(const bf16x8*)&Ks[f * 16 + lcol][32 + hi * 8];
        s4 = __builtin_amdgcn_mfma_f32_16x16x32_bf16(ka0, qf0, s4, 0, 0, 0);
        s4 = __builtin_amdgcn_mfma_f32_16x16x32_bf16(ka1, qf1, s4, 0, 0, 0);
        f32x4 pw;
        bf16x4 pb;
#pragma unroll
        for (int i = 0; i < 4; ++i) {
          const int t = t0 + f * 16 + hi * 4 + i;
          const float v = (t <= qrow) ? s4[i] * scale : -1e30f;
          const float pr = __expf(v - m_fin) * inv;
          pw[i] = pr;
          pb[i] = (bf16_t)pr;
        }
        __builtin_nontemporal_store(pw, (f32x4*)&probs[prow + t0 + f * 16 + hi * 4]);
        *(bf16x4*)&Ps[wq * 16 + lcol][f * 16 + hi * 4] = pb;
      } else {
        __builtin_nontemporal_store(zf, (f32x4*)&probs[prow + t0 + f * 16 + hi * 4]);
        *(bf16x4*)&Ps[wq * 16 + lcol][f * 16 + hi * 4] = zb;
      }
    }

#pragma unroll
    for (int ks = 0; ks < 4; ++ks) {
      const bf16x8 pf = *(const bf16x8*)&Ps[wq * 16 + lcol][ks * 32 + hi * 8];
#pragma unroll
      for (int df = 0; df < 4; ++df) {
        const bf16x8 vf = *(const bf16x8*)&Vs[df * 16 + lcol][ks * 32 + hi * 8];
        cacc[df] = __builtin_amdgcn_mfma_f32_16x16x32_bf16(vf, pf, cacc[df], 0, 0, 0);
      }
    }
    __syncthreads();
  }

#pragma unroll
  for (int df = 0; df < 4; ++df) {
    bf16x4 o;
#pragma unroll
    for (int i = 0; i < 4; ++i) o[i] = (bf16_t)cacc[df][i];
    *(bf16x4*)&ctxcat[((size_t)(b * NS + qrow)) * 2048 + quar * 512 + h * NDK + df * 16 + hi * 4] = o;
  }
}

// ---------------------------------------------------------------- launch
extern "C" void kernel_launch(void* const* d_in, const int* in_sizes, int n_in,
                              void* d_out, int out_size, void* d_ws, size_t ws_size,
                              hipStream_t stream) {
  const int*   tokens  = (const int*)d_in[0];
  const float* tok_emb = (const float*)d_in[1];
  const float* Wq = (const float*)d_in[2];
  const float* bq = (const float*)d_in[3];
  const float* Wk = (const float*)d_in[4];
  const float* bk = (const float*)d_in[5];
  const float* Wv = (const float*)d_in[6];
  const float* bv = (const float*)d_in[7];
  const float* Wo = (const float*)d_in[8];
  const float* bo = (const float*)d_in[9];
  const float* ln1_g = (const float*)d_in[10];
  const float* ln1_b = (const float*)d_in[11];
  const float* W1 = (const float*)d_in[12];
  const float* b1 = (const float*)d_in[13];
  const float* W2 = (const float*)d_in[14];
  const float* b2 = (const float*)d_in[15];
  const float* ln2_g = (const float*)d_in[16];
  const float* ln2_b = (const float*)d_in[17];
  const float* lnf_g = (const float*)d_in[18];
  const float* lnf_b = (const float*)d_in[19];
  const float* Wout = (const float*)d_in[20];
  const float* bout = (const float*)d_in[21];

  float* logits   = (float*)d_out;                               // [B,S,V]
  float* attn_all = (float*)d_out + (size_t)NB * NS * NV;        // [L,B,H,S,S]

  char* w = (char*)d_ws;
  float* x    = (float*)w;  w += (size_t)4 << 20;
  float* tmp  = (float*)w;  w += (size_t)8 << 20;   // two 4MB split-K halves
  bf16_t* xb  = (bf16_t*)w; w += (size_t)2 << 20;
  bf16_t* qkv = (bf16_t*)w; w += (size_t)6 << 20;
  float* marr = (float*)w;                          // 256KB stats (4 quarters)
  float* sarr = (float*)(w + (1 << 20));            // 256KB
  w += (size_t)2 << 20;
  bf16_t* hh  = (bf16_t*)w;                         // [M][2048] (FF1)
  bf16_t* ctxcat = (bf16_t*)w;                      // [M][2048] overlays hh (disjoint lifetime)
  w += (size_t)8 << 20;
  bf16_t* WqkvT = (bf16_t*)w; w += (size_t)6 * QKVLD * ND * 2;
  bf16_t* WoT   = (bf16_t*)w; w += (size_t)6 * ND * ND * 2;
  bf16_t* W1T   = (bf16_t*)w; w += (size_t)6 * NDFF * ND * 2;
  bf16_t* W2T   = (bf16_t*)w; w += (size_t)6 * ND * NDFF * 2;
  bf16_t* WoutT = (bf16_t*)w; w += (size_t)NV * ND * 2;
  if ((size_t)(w - (char*)d_ws) > ws_size) return;

  const int M = MROWS;
  const size_t U = (size_t)M * ND;         // elements per split-K half
  float* tmp1 = tmp + U;

  prep_kernel<<<10656, 256, 0, stream>>>(tokens, tok_emb, Wq, Wk, Wv, Wo, W1, W2, Wout,
                                         WqkvT, WoT, W1T, W2T, WoutT, x, xb);

  const dim3 gQKV(M / 64, QKVLD / 64);     // (32, 24) = 768 blocks
  const dim3 gFF1(M / 64, NDFF / 64);      // (32, 32) = 1024 blocks
  const dim3 gOut(M / 128, NV / 128);      // (16, 250)
  const dim3 g64s(M / 64, ND / 64, 2);     // (32, 8, 2) = 512 blocks, split-K
  const dim3 gAttn(16, NH, NB * 4);        // (16, 8, 8) = 1024 blocks, t-quarter split

  const int ALLK = 0x7fffffff;

  for (int l = 0; l < NL; ++l) {
    gemm_qkv64<<<gQKV, 256, 0, stream>>>(xb, WqkvT + (size_t)l * QKVLD * ND,
        bq + l * ND, bk + l * ND, bv + l * ND, qkv, ND, ND, QKVLD);

    float* probs_l = attn_all + (size_t)l * NB * NH * NS * NS;
    attn_stats<<<gAttn, 256, 0, stream>>>(qkv, marr, sarr, probs_l);
    attn_pv<<<gAttn, 256, 0, stream>>>(qkv, marr, sarr, probs_l, ctxcat);

    // Wo: K=2048 over ctxcat quarters, W col index mod 512 (kmask)
    gemm64<0, 0><<<g64s, 256, 0, stream>>>(ctxcat, WoT + (size_t)l * ND * ND,
        bo + l * ND, tmp, 2048, 2048, ND, 511, ND, U);
    add_ln_kernel<<<M, 256, 0, stream>>>(x, tmp, tmp1,
        ln1_g + l * ND, ln1_b + l * ND, nullptr, nullptr, xb);

    gemm64<1, 1><<<gFF1, 256, 0, stream>>>(xb, W1T + (size_t)l * NDFF * ND,
        b1 + l * NDFF, hh, ND, ND, ND, ALLK, NDFF, 0);
    gemm64<0, 0><<<g64s, 256, 0, stream>>>(hh, W2T + (size_t)l * ND * NDFF,
        b2 + l * ND, tmp, NDFF, NDFF, NDFF, ALLK, ND, U);
    // last layer: fuse the final lnf into this LN
    add_ln_kernel<<<M, 256, 0, stream>>>(x, tmp, tmp1,
        ln2_g + l * ND, ln2_b + l * ND,
        (l == NL - 1) ? lnf_g : nullptr, (l == NL - 1) ? lnf_b : nullptr, xb);
  }

  gemm_bt<0, 0><<<gOut, 256, 0, stream>>>(xb, WoutT, bout,
      logits, NV, ND, ND, NV);
}

// Round 16
// 657.996 us; speedup vs baseline: 1.0261x; 1.0261x over previous
//
#include <hip/hip_runtime.h>
#include <math.h>

#define NB 2
#define NS 1024
#define NH 8
#define NDK 64
#define ND 512
#define NDFF 2048
#define NV 32000
#define NL 6
#define MROWS (NB * NS)
#define QKVLD (3 * ND)   // 1536

using bf16_t = __bf16;
using bf16x4 = __attribute__((ext_vector_type(4))) __bf16;
using bf16x8 = __attribute__((ext_vector_type(8))) __bf16;
using f32x4  = __attribute__((ext_vector_type(4))) float;

__device__ __forceinline__ void gload_lds16(const bf16_t* g, bf16_t* l) {
  __builtin_amdgcn_global_load_lds(
      (const __attribute__((address_space(1))) void*)g,
      (__attribute__((address_space(3))) void*)l, 16, 0, 0);
}

__device__ __forceinline__ float gelu_exact(float v) {
  return 0.5f * v * (1.0f + erff(v * 0.7071067811865476f));
}

// ---------------------------------------------------------------- prep: all weight transposes + embed
__global__ __launch_bounds__(256)
void prep_kernel(const int* __restrict__ tokens, const float* __restrict__ emb,
                 const float* __restrict__ Wq, const float* __restrict__ Wk,
                 const float* __restrict__ Wv, const float* __restrict__ Wo,
                 const float* __restrict__ W1, const float* __restrict__ W2,
                 const float* __restrict__ Wout,
                 bf16_t* __restrict__ WqkvT, bf16_t* __restrict__ WoT,
                 bf16_t* __restrict__ W1T, bf16_t* __restrict__ W2T,
                 bf16_t* __restrict__ WoutT,
                 float* __restrict__ x, bf16_t* __restrict__ xb) {
  __shared__ bf16_t T[64][72];
  const int id = blockIdx.x;
  const int tid = threadIdx.x;

  if (id >= 8608) {                       // ---- embed
    const int row = id - 8608;            // b*NS + s
    const int s = row & (NS - 1);
    const int tok = tokens[row];
    const float SQRTD = 22.627416997969522f;
    const float C = -9.210340371976184f / (float)ND;
#pragma unroll
    for (int i = 0; i < 2; ++i) {
      const int d = tid + i * 256;
      const int pair = d >> 1;
      const float div = expf((float)(2 * pair) * C);
      const float ang = (float)s * div;
      const float pe = (d & 1) ? cosf(ang) : sinf(ang);
      const float v = emb[(size_t)tok * ND + d] * SQRTD + pe;
      x[(size_t)row * ND + d] = v;
      xb[(size_t)row * ND + d] = (bf16_t)v;
    }
    return;
  }

  const float* src; bf16_t* dst; int K, N, n0, k0;
  if (id < 1536) {                        // Wq/Wk/Wv/Wo, 512x512 each
    const int z = id >> 6, t = id & 63;
    const int mat = z / 6, layer = z % 6;
    src = ((mat == 0) ? Wq : (mat == 1) ? Wk : (mat == 2) ? Wv : Wo) + (size_t)layer * ND * ND;
    dst = (mat < 3) ? (WqkvT + (size_t)layer * QKVLD * ND + (size_t)mat * ND * ND)
                    : (WoT + (size_t)layer * ND * ND);
    K = ND; N = ND; n0 = (t & 7) * 64; k0 = (t >> 3) * 64;
  } else if (id < 3072) {                 // W1: [512][2048]
    const int idx = id - 1536, layer = idx >> 8, t = idx & 255;
    src = W1 + (size_t)layer * ND * NDFF; dst = W1T + (size_t)layer * NDFF * ND;
    K = ND; N = NDFF; n0 = (t & 31) * 64; k0 = (t >> 5) * 64;
  } else if (id < 4608) {                 // W2: [2048][512]
    const int idx = id - 3072, layer = idx >> 8, t = idx & 255;
    src = W2 + (size_t)layer * NDFF * ND; dst = W2T + (size_t)layer * ND * NDFF;
    K = NDFF; N = ND; n0 = (t & 7) * 64; k0 = (t >> 3) * 64;
  } else {                                // Wout: [512][32000]
    const int t = id - 4608;
    src = Wout; dst = WoutT;
    K = ND; N = NV; n0 = (t % 500) * 64; k0 = (t / 500) * 64;
  }

#pragma unroll
  for (int it = 0; it < 4; ++it) {
    const int k = (tid >> 4) + it * 16;
    const int c = (tid & 15) * 4;
    const float4 v = *(const float4*)&src[(size_t)(k0 + k) * N + n0 + c];
    T[c + 0][k] = (bf16_t)v.x;
    T[c + 1][k] = (bf16_t)v.y;
    T[c + 2][k] = (bf16_t)v.z;
    T[c + 3][k] = (bf16_t)v.w;
  }
  __syncthreads();
  const int n = tid >> 2, kk = (tid & 3) * 16;
  bf16x8 a = *(const bf16x8*)&T[n][kk];
  bf16x8 b2v = *(const bf16x8*)&T[n][kk + 8];
  *(bf16x8*)&dst[(size_t)(n0 + n) * K + k0 + kk] = a;
  *(bf16x8*)&dst[(size_t)(n0 + n) * K + k0 + kk + 8] = b2v;
}

// ---------------------------------------------------------------- residual add (two partials) + LayerNorm (+ optional second LN)
__global__ __launch_bounds__(256)
void add_ln_kernel(float* __restrict__ x, const float* __restrict__ y0,
                   const float* __restrict__ y1,
                   const float* __restrict__ g, const float* __restrict__ bb,
                   const float* __restrict__ g2, const float* __restrict__ bb2,
                   bf16_t* __restrict__ xb) {
  const int row = blockIdx.x, tid = threadIdx.x;
  const size_t base = (size_t)row * ND;
  float v0 = x[base + tid], v1 = x[base + tid + 256];
  if (y0) { v0 += y0[base + tid]; v1 += y0[base + tid + 256]; }
  if (y1) { v0 += y1[base + tid]; v1 += y1[base + tid + 256]; }
  __shared__ float red[256];
  red[tid] = v0 + v1; __syncthreads();
  for (int o = 128; o > 0; o >>= 1) {
    if (tid < o) red[tid] += red[tid + o];
    __syncthreads();
  }
  const float mean = red[0] * (1.f / (float)ND);
  __syncthreads();
  const float d0 = v0 - mean, d1 = v1 - mean;
  red[tid] = d0 * d0 + d1 * d1; __syncthreads();
  for (int o = 128; o > 0; o >>= 1) {
    if (tid < o) red[tid] += red[tid + o];
    __syncthreads();
  }
  const float inv = 1.f / sqrtf(red[0] * (1.f / (float)ND) + 1e-5f);
  float o0 = d0 * inv * g[tid]       + bb[tid];
  float o1 = d1 * inv * g[tid + 256] + bb[tid + 256];

  if (g2) {       // fused second LayerNorm (final lnf)
    __syncthreads();
    red[tid] = o0 + o1; __syncthreads();
    for (int o = 128; o > 0; o >>= 1) {
      if (tid < o) red[tid] += red[tid + o];
      __syncthreads();
    }
    const float mean2 = red[0] * (1.f / (float)ND);
    __syncthreads();
    const float e0 = o0 - mean2, e1 = o1 - mean2;
    red[tid] = e0 * e0 + e1 * e1; __syncthreads();
    for (int o = 128; o > 0; o >>= 1) {
      if (tid < o) red[tid] += red[tid + o];
      __syncthreads();
    }
    const float inv2 = 1.f / sqrtf(red[0] * (1.f / (float)ND) + 1e-5f);
    o0 = e0 * inv2 * g2[tid]       + bb2[tid];
    o1 = e1 * inv2 * g2[tid + 256] + bb2[tid + 256];
  } else {
    x[base + tid] = o0;
    x[base + tid + 256] = o1;
  }
  xb[base + tid] = (bf16_t)o0; xb[base + tid + 256] = (bf16_t)o1;
}

// ---------------------------------------------------------------- 128x128 GEMM, BK=64 (logits), XCD swizzle
template <int ACT, int OUTBF>
__global__ __launch_bounds__(256)
void gemm_bt(const bf16_t* __restrict__ A, const bf16_t* __restrict__ Wt,
             const float* __restrict__ B0,
             void* __restrict__ Cout, int N, int K, int lda, int ldc) {
  __shared__ bf16_t As[128 * 64];
  __shared__ bf16_t Bs[128 * 64];
  const int tid = threadIdx.x, lane = tid & 63, w = tid >> 6;
  const int wm = w >> 1, wn = w & 1;
  const int lcol = lane & 15, hi = lane >> 4;

  // bijective XCD swizzle (m204)
  const int nwg = gridDim.x * gridDim.y;
  const int flat = blockIdx.y * gridDim.x + blockIdx.x;
  const int q = nwg >> 3, r = nwg & 7;
  const int xcd = flat & 7, idx = flat >> 3;
  const int nf = (xcd < r ? xcd * (q + 1) : r * (q + 1) + (xcd - r) * q) + idx;
  const int m0 = (nf % gridDim.x) * 128, n0 = (nf / gridDim.x) * 128;

  const int sr8 = lane >> 3;        // 0..7
  const int sslot = lane & 7;       // 16B slot 0..7

  f32x4 acc[4][4] = {};

  for (int k0 = 0; k0 < K; k0 += 64) {
#pragma unroll
    for (int t = 0; t < 2; ++t) {
#pragma unroll
      for (int c = 0; c < 2; ++c) {
        const int rbase = t * 64 + w * 16 + c * 8;     // wave-uniform
        const int row = rbase + sr8;
        const int ks = sslot ^ (row & 7);
        gload_lds16(&A[(size_t)(m0 + row) * lda + k0 + ks * 8], &As[rbase * 64]);
        gload_lds16(&Wt[(size_t)(n0 + row) * K + k0 + ks * 8], &Bs[rbase * 64]);
      }
    }
    __syncthreads();

#pragma unroll
    for (int kk = 0; kk < 2; ++kk) {
      bf16x8 af[4], bf[4];
#pragma unroll
      for (int m = 0; m < 4; ++m) {
        const int rr = wm * 64 + m * 16 + lcol;
        af[m] = *(const bf16x8*)&As[rr * 64 + (((kk * 4 + hi) ^ (rr & 7)) * 8)];
      }
#pragma unroll
      for (int n = 0; n < 4; ++n) {
        const int rr = wn * 64 + n * 16 + lcol;
        bf[n] = *(const bf16x8*)&Bs[rr * 64 + (((kk * 4 + hi) ^ (rr & 7)) * 8)];
      }
#pragma unroll
      for (int m = 0; m < 4; ++m)
#pragma unroll
        for (int n = 0; n < 4; ++n)
          acc[m][n] = __builtin_amdgcn_mfma_f32_16x16x32_bf16(bf[n], af[m], acc[m][n], 0, 0, 0);
    }
    __syncthreads();
  }

#pragma unroll
  for (int m = 0; m < 4; ++m) {
    const int row = m0 + wm * 64 + m * 16 + lcol;
#pragma unroll
    for (int n = 0; n < 4; ++n) {
      const int col = n0 + wn * 64 + n * 16 + hi * 4;
      const f32x4 bv = *(const f32x4*)&B0[col];
      f32x4 v;
#pragma unroll
      for (int i = 0; i < 4; ++i) {
        float t = acc[m][n][i] + bv[i];
        if (ACT == 1) t = gelu_exact(t);
        v[i] = t;
      }
      if (OUTBF) {
        bf16x4 o;
#pragma unroll
        for (int i = 0; i < 4; ++i) o[i] = (bf16_t)v[i];
        *(bf16x4*)&((bf16_t*)Cout)[(size_t)row * ldc + col] = o;
      } else {
        __builtin_nontemporal_store(v, (f32x4*)&((float*)Cout)[(size_t)row * ldc + col]);
      }
    }
  }
}

// ---------------------------------------------------------------- 64x64 GEMM, BK=128, 3-way bias (QKV), bf16 out
__global__ __launch_bounds__(256)
void gemm_qkv64(const bf16_t* __restrict__ A, const bf16_t* __restrict__ Wt,
                const float* __restrict__ B0, const float* __restrict__ B1,
                const float* __restrict__ B2,
                bf16_t* __restrict__ Cout, int K, int lda, int ldc) {
  __shared__ bf16_t As[64 * 128];   // 16KB each, row stride 256B, 16 slots
  __shared__ bf16_t Bs[64 * 128];
  const int tid = threadIdx.x, lane = tid & 63, w = tid >> 6;
  const int wm = w >> 1, wn = w & 1;
  const int lcol = lane & 15, hi = lane >> 4;
  const int m0 = blockIdx.x * 64, n0 = blockIdx.y * 64;
  const int sr4 = lane >> 4, sslot = lane & 15;

  f32x4 acc[2][2] = {};

  for (int k0 = 0; k0 < K; k0 += 128) {
#pragma unroll
    for (int c = 0; c < 4; ++c) {
      const int rbase = w * 16 + c * 4;                // wave-uniform
      const int row = rbase + sr4;
      const int ks = sslot ^ (row & 15);
      gload_lds16(&A[(size_t)(m0 + row) * lda + k0 + ks * 8], &As[rbase * 128]);
      gload_lds16(&Wt[(size_t)(n0 + row) * K + k0 + ks * 8], &Bs[rbase * 128]);
    }
    __syncthreads();

#pragma unroll
    for (int kk = 0; kk < 4; ++kk) {
      bf16x8 af[2], bf[2];
#pragma unroll
      for (int m = 0; m < 2; ++m) {
        const int rr = wm * 32 + m * 16 + lcol;
        af[m] = *(const bf16x8*)&As[rr * 128 + (((kk * 4 + hi) ^ (rr & 15)) * 8)];
      }
#pragma unroll
      for (int n = 0; n < 2; ++n) {
        const int rr = wn * 32 + n * 16 + lcol;
        bf[n] = *(const bf16x8*)&Bs[rr * 128 + (((kk * 4 + hi) ^ (rr & 15)) * 8)];
      }
#pragma unroll
      for (int m = 0; m < 2; ++m)
#pragma unroll
        for (int n = 0; n < 2; ++n)
          acc[m][n] = __builtin_amdgcn_mfma_f32_16x16x32_bf16(bf[n], af[m], acc[m][n], 0, 0, 0);
    }
    __syncthreads();
  }

#pragma unroll
  for (int m = 0; m < 2; ++m) {
    const int row = m0 + wm * 32 + m * 16 + lcol;
#pragma unroll
    for (int n = 0; n < 2; ++n) {
      const int col = n0 + wn * 32 + n * 16 + hi * 4;
      const int sel = col >> 9;
      const float* Bp = (sel == 0) ? B0 : (sel == 1) ? B1 : B2;
      const f32x4 bv = *(const f32x4*)&Bp[col & 511];
      bf16x4 o;
#pragma unroll
      for (int i = 0; i < 4; ++i) o[i] = (bf16_t)(acc[m][n][i] + bv[i]);
      *(bf16x4*)&Cout[(size_t)row * ldc + col] = o;
    }
  }
}

// ---------------------------------------------------------------- 64x64 GEMM, BK=128, single bias, optional split-K
// Wt col index = (k & kmask) so a wide-K A (concatenated partials) can share one [N][512] W.
template <int ACT, int OUTBF>
__global__ __launch_bounds__(256)
void gemm64(const bf16_t* __restrict__ A, const bf16_t* __restrict__ Wt,
            const float* __restrict__ bias,
            void* __restrict__ Cout, int K, int lda, int ldw, int kmask,
            int ldc, size_t zstride) {
  __shared__ bf16_t As[64 * 128];
  __shared__ bf16_t Bs[64 * 128];
  const int tid = threadIdx.x, lane = tid & 63, w = tid >> 6;
  const int wm = w >> 1, wn = w & 1;
  const int lcol = lane & 15, hi = lane >> 4;
  const int m0 = blockIdx.x * 64, n0 = blockIdx.y * 64;
  const int sr4 = lane >> 4, sslot = lane & 15;
  const int kc = K / gridDim.z;
  const int kbeg = blockIdx.z * kc;

  f32x4 acc[2][2] = {};

  for (int k0 = kbeg; k0 < kbeg + kc; k0 += 128) {
#pragma unroll
    for (int c = 0; c < 4; ++c) {
      const int rbase = w * 16 + c * 4;
      const int row = rbase + sr4;
      const int ks = sslot ^ (row & 15);
      gload_lds16(&A[(size_t)(m0 + row) * lda + k0 + ks * 8], &As[rbase * 128]);
      gload_lds16(&Wt[(size_t)(n0 + row) * ldw + ((k0 & kmask) + ks * 8)], &Bs[rbase * 128]);
    }
    __syncthreads();

#pragma unroll
    for (int kk = 0; kk < 4; ++kk) {
      bf16x8 af[2], bf[2];
#pragma unroll
      for (int m = 0; m < 2; ++m) {
        const int rr = wm * 32 + m * 16 + lcol;
        af[m] = *(const bf16x8*)&As[rr * 128 + (((kk * 4 + hi) ^ (rr & 15)) * 8)];
      }
#pragma unroll
      for (int n = 0; n < 2; ++n) {
        const int rr = wn * 32 + n * 16 + lcol;
        bf[n] = *(const bf16x8*)&Bs[rr * 128 + (((kk * 4 + hi) ^ (rr & 15)) * 8)];
      }
#pragma unroll
      for (int m = 0; m < 2; ++m)
#pragma unroll
        for (int n = 0; n < 2; ++n)
          acc[m][n] = __builtin_amdgcn_mfma_f32_16x16x32_bf16(bf[n], af[m], acc[m][n], 0, 0, 0);
    }
    __syncthreads();
  }

#pragma unroll
  for (int m = 0; m < 2; ++m) {
    const int row = m0 + wm * 32 + m * 16 + lcol;
#pragma unroll
    for (int n = 0; n < 2; ++n) {
      const int col = n0 + wn * 32 + n * 16 + hi * 4;
      f32x4 bv = {0.f, 0.f, 0.f, 0.f};
      if (blockIdx.z == 0) bv = *(const f32x4*)&bias[col];
      f32x4 v;
#pragma unroll
      for (int i = 0; i < 4; ++i) {
        float t = acc[m][n][i] + bv[i];
        if (ACT == 1) t = gelu_exact(t);
        v[i] = t;
      }
      if (OUTBF) {
        bf16x4 o;
#pragma unroll
        for (int i = 0; i < 4; ++i) o[i] = (bf16_t)v[i];
        *(bf16x4*)&((bf16_t*)Cout)[(size_t)row * ldc + col] = o;
      } else {
        *(f32x4*)&((float*)Cout)[blockIdx.z * zstride + (size_t)row * ldc + col] = v;
      }
    }
  }
}

// ---------------------------------------------------------------- attention stats: partial (m,s) per t-half
// grid (16, NH, NB*2); z -> b = z>>1, half = z&1. Tiles tt = half, half+2, ...
// Q fragments read directly from global (once per block); LDS = Ks only.
__global__ __launch_bounds__(256)
void attn_stats(const bf16_t* __restrict__ qkv,
                float* __restrict__ marr, float* __restrict__ sarr,
                float* __restrict__ probs) {
  const int qt = 15 - blockIdx.x;            // heavy blocks first
  const int h = blockIdx.y;
  const int b = blockIdx.z >> 1, half = blockIdx.z & 1;
  const int q0 = qt * 64;
  const int NTT = (q0 >> 7) + 1;
  const int qmax = q0 + 63;
  const int tid = threadIdx.x, lane = tid & 63, wq = tid >> 6;
  const int lcol = lane & 15, hi = lane >> 4;

  __shared__ bf16_t Ks[128][72];

  // zero-fill probs tail (half 0 only) — overlaps other blocks' compute
  if (half == 0) {
    const int z0 = NTT * 128;
    const int nz = (NS - z0) >> 2;
    if (nz > 0) {
      const f32x4 zf = {0.f, 0.f, 0.f, 0.f};
      for (int idx = tid; idx < 64 * nz; idx += 256) {
        const int r = idx / nz, c = (idx - r * nz) * 4;
        __builtin_nontemporal_store(zf,
            (f32x4*)&probs[(((size_t)b * NH + h) * NS + q0 + r) * NS + z0 + c]);
      }
    }
  }

  const int qrow = q0 + wq * 16 + lcol;
  const bf16_t* qsrc = &qkv[((size_t)(b * NS + qrow)) * QKVLD + h * NDK + hi * 8];
  const bf16x8 qf0 = *(const bf16x8*)qsrc;
  const bf16x8 qf1 = *(const bf16x8*)(qsrc + 32);
  const float scale = 0.125f;

  float m_run = -1e30f, s_run = 0.f;

  for (int tt = half; tt < NTT; tt += 2) {
    const int t0 = tt * 128;
    const int fmax = min(8, ((qmax - t0) >> 4) + 1);
    {
      const int r = tid >> 1, cb = (tid & 1) * 32;
      const bf16_t* src = &qkv[((size_t)(b * NS + t0 + r)) * QKVLD + ND + h * NDK + cb];
#pragma unroll
      for (int j = 0; j < 4; ++j)
        *(bf16x8*)&Ks[r][cb + j * 8] = *(const bf16x8*)&src[j * 8];
    }
    __syncthreads();

    float tmax = -1e30f;
    f32x4 sc[8];
#pragma unroll
    for (int f = 0; f < 8; ++f) {
      if (f >= fmax) break;
      f32x4 s4 = {};
      const bf16x8 ka0 = *(const bf16x8*)&Ks[f * 16 + lcol][hi * 8];
      const bf16x8 ka1 = *(const bf16x8*)&Ks[f * 16 + lcol][32 + hi * 8];
      s4 = __builtin_amdgcn_mfma_f32_16x16x32_bf16(ka0, qf0, s4, 0, 0, 0);
      s4 = __builtin_amdgcn_mfma_f32_16x16x32_bf16(ka1, qf1, s4, 0, 0, 0);
#pragma unroll
      for (int i = 0; i < 4; ++i) {
        const int t = t0 + f * 16 + hi * 4 + i;
        const float v = (t <= qrow) ? s4[i] * scale : -1e30f;
        s4[i] = v;
        tmax = fmaxf(tmax, v);
      }
      sc[f] = s4;
    }
    tmax = fmaxf(tmax, __shfl_xor(tmax, 16));
    tmax = fmaxf(tmax, __shfl_xor(tmax, 32));
    const float m_new = fmaxf(m_run, tmax);
    float sum = 0.f;
#pragma unroll
    for (int f = 0; f < 8; ++f) {
      if (f >= fmax) break;
#pragma unroll
      for (int i = 0; i < 4; ++i) sum += __expf(sc[f][i] - m_new);
    }
    sum += __shfl_xor(sum, 16);
    sum += __shfl_xor(sum, 32);
    s_run = s_run * __expf(m_run - m_new) + sum;
    m_run = m_new;
    __syncthreads();
  }

  if (hi == 0) {
    const size_t idx = (((size_t)half * NB + b) * NH + h) * NS + qrow;
    marr[idx] = m_run;
    sarr[idx] = s_run;
  }
}

// ---------------------------------------------------------------- attention probs+PV, t-half split, merged stats
// ctxcat: [M][1024] bf16, half h writes cols [h*512 + head*64 .. +64)
// Q fragments read directly from global; LDS = Ks + Vs + Ps (52KB -> 3 blocks/CU).
__global__ __launch_bounds__(256)
void attn_pv(const bf16_t* __restrict__ qkv,
             const float* __restrict__ marr, const float* __restrict__ sarr,
             float* __restrict__ probs, bf16_t* __restrict__ ctxcat) {
  const int qt = 15 - blockIdx.x;
  const int h = blockIdx.y;
  const int b = blockIdx.z >> 1, half = blockIdx.z & 1;
  const int q0 = qt * 64;
  const int NTT = (q0 >> 7) + 1;
  const int qmax = q0 + 63;
  const int tid = threadIdx.x, lane = tid & 63, wq = tid >> 6;
  const int lcol = lane & 15, hi = lane >> 4;

  __shared__ bf16_t Ks[128][72];
  __shared__ bf16_t Vs[64][132];
  __shared__ bf16_t Ps[64][132];

  const int qrow = q0 + wq * 16 + lcol;
  const bf16_t* qsrc = &qkv[((size_t)(b * NS + qrow)) * QKVLD + h * NDK + hi * 8];
  const bf16x8 qf0 = *(const bf16x8*)qsrc;
  const bf16x8 qf1 = *(const bf16x8*)(qsrc + 32);
  const float scale = 0.125f;

  // merge the two partial stats
  const size_t i0 = (((size_t)0 * NB + b) * NH + h) * NS + qrow;
  const size_t i1 = (((size_t)1 * NB + b) * NH + h) * NS + qrow;
  const float m0 = marr[i0], m1 = marr[i1];
  const float s0 = sarr[i0], s1 = sarr[i1];
  const float m_fin = fmaxf(m0, m1);
  const float s_fin = s0 * __expf(m0 - m_fin) + s1 * __expf(m1 - m_fin);
  const float inv = 1.f / s_fin;

  f32x4 cacc[4] = {};
  const size_t prow = (((size_t)b * NH + h) * NS + qrow) * NS;
  for (int tt = half; tt < NTT; tt += 2) {
    const int t0 = tt * 128;
    const int fmax = min(8, ((qmax - t0) >> 4) + 1);
    {
      const int r = tid >> 1, cb = (tid & 1) * 32;
      const bf16_t* src = &qkv[((size_t)(b * NS + t0 + r)) * QKVLD + ND + h * NDK + cb];
#pragma unroll
      for (int j = 0; j < 4; ++j)
        *(bf16x8*)&Ks[r][cb + j * 8] = *(const bf16x8*)&src[j * 8];
    }
    {
      // V: register 4x4 transpose -> vectorized b64 LDS stores
#pragma unroll
      for (int it = 0; it < 2; ++it) {
        const int t4 = (tid >> 4) * 4 + it * 64;
        const int dk4 = (tid & 15) * 4;
        bf16x4 rr[4];
#pragma unroll
        for (int i = 0; i < 4; ++i)
          rr[i] = *(const bf16x4*)&qkv[((size_t)(b * NS + t0 + t4 + i)) * QKVLD + 2 * ND + h * NDK + dk4];
#pragma unroll
        for (int j = 0; j < 4; ++j) {
          bf16x4 c;
#pragma unroll
          for (int i = 0; i < 4; ++i) c[i] = rr[i][j];
          *(bf16x4*)&Vs[dk4 + j][t4] = c;
        }
      }
    }
    __syncthreads();

    const f32x4 zf = {0.f, 0.f, 0.f, 0.f};
    const bf16x4 zb = {(bf16_t)0.f, (bf16_t)0.f, (bf16_t)0.f, (bf16_t)0.f};
#pragma unroll
    for (int f = 0; f < 8; ++f) {
      if (f < fmax) {
        f32x4 s4 = {};
        const bf16x8 ka0 = *(const bf16x8*)&Ks[f * 16 + lcol][hi * 8];
        const bf16x8 ka1 = *(const bf16x8*)&Ks[f * 16 + lcol][32 + hi * 8];
        s4 = __builtin_amdgcn_mfma_f32_16x16x32_bf16(ka0, qf0, s4, 0, 0, 0);
        s4 = __builtin_amdgcn_mfma_f32_16x16x32_bf16(ka1, qf1, s4, 0, 0, 0);
        f32x4 pw;
        bf16x4 pb;
#pragma unroll
        for (int i = 0; i < 4; ++i) {
          const int t = t0 + f * 16 + hi * 4 + i;
          const float v = (t <= qrow) ? s4[i] * scale : -1e30f;
          const float pr = __expf(v - m_fin) * inv;
          pw[i] = pr;
          pb[i] = (bf16_t)pr;
        }
        __builtin_nontemporal_store(pw, (f32x4*)&probs[prow + t0 + f * 16 + hi * 4]);
        *(bf16x4*)&Ps[wq * 16 + lcol][f * 16 + hi * 4] = pb;
      } else {
        __builtin_nontemporal_store(zf, (f32x4*)&probs[prow + t0 + f * 16 + hi * 4]);
        *(bf16x4*)&Ps[wq * 16 + lcol][f * 16 + hi * 4] = zb;
      }
    }

#pragma unroll
    for (int ks = 0; ks < 4; ++ks) {
      const bf16x8 pf = *(const bf16x8*)&Ps[wq * 16 + lcol][ks * 32 + hi * 8];
#pragma unroll
      for (int df = 0; df < 4; ++df) {
        const bf16x8 vf = *(const bf16x8*)&Vs[df * 16 + lcol][ks * 32 + hi * 8];
        cacc[df] = __builtin_amdgcn_mfma_f32_16x16x32_bf16(vf, pf, cacc[df], 0, 0, 0);
      }
    }
    __syncthreads();
  }

#pragma unroll
  for (int df = 0; df < 4; ++df) {
    bf16x4 o;
#pragma unroll
    for (int i = 0; i < 4; ++i) o[i] = (bf16_t)cacc[df][i];
    *(bf16x4*)&ctxcat[((size_t)(b * NS + qrow)) * 1024 + half * 512 + h * NDK + df * 16 + hi * 4] = o;
  }
}

// ---------------------------------------------------------------- launch
extern "C" void kernel_launch(void* const* d_in, const int* in_sizes, int n_in,
                              void* d_out, int out_size, void* d_ws, size_t ws_size,
                              hipStream_t stream) {
  const int*   tokens  = (const int*)d_in[0];
  const float* tok_emb = (const float*)d_in[1];
  const float* Wq = (const float*)d_in[2];
  const float* bq = (const float*)d_in[3];
  const float* Wk = (const float*)d_in[4];
  const float* bk = (const float*)d_in[5];
  const float* Wv = (const float*)d_in[6];
  const float* bv = (const float*)d_in[7];
  const float* Wo = (const float*)d_in[8];
  const float* bo = (const float*)d_in[9];
  const float* ln1_g = (const float*)d_in[10];
  const float* ln1_b = (const float*)d_in[11];
  const float* W1 = (const float*)d_in[12];
  const float* b1 = (const float*)d_in[13];
  const float* W2 = (const float*)d_in[14];
  const float* b2 = (const float*)d_in[15];
  const float* ln2_g = (const float*)d_in[16];
  const float* ln2_b = (const float*)d_in[17];
  const float* lnf_g = (const float*)d_in[18];
  const float* lnf_b = (const float*)d_in[19];
  const float* Wout = (const float*)d_in[20];
  const float* bout = (const float*)d_in[21];

  float* logits   = (float*)d_out;                               // [B,S,V]
  float* attn_all = (float*)d_out + (size_t)NB * NS * NV;        // [L,B,H,S,S]

  char* w = (char*)d_ws;
  float* x    = (float*)w;  w += (size_t)4 << 20;
  float* tmp  = (float*)w;  w += (size_t)8 << 20;   // two 4MB split-K halves
  bf16_t* xb  = (bf16_t*)w; w += (size_t)2 << 20;
  bf16_t* qkv = (bf16_t*)w; w += (size_t)6 << 20;
  float* marr = (float*)w;                          // 128KB stats (2 halves)
  float* sarr = (float*)(w + (512 << 10));          // 128KB
  w += (size_t)2 << 20;
  bf16_t* hh  = (bf16_t*)w;                         // [M][2048] (FF1)
  bf16_t* ctxcat = (bf16_t*)w;                      // [M][1024] overlays hh (disjoint lifetime)
  w += (size_t)8 << 20;
  bf16_t* WqkvT = (bf16_t*)w; w += (size_t)6 * QKVLD * ND * 2;
  bf16_t* WoT   = (bf16_t*)w; w += (size_t)6 * ND * ND * 2;
  bf16_t* W1T   = (bf16_t*)w; w += (size_t)6 * NDFF * ND * 2;
  bf16_t* W2T   = (bf16_t*)w; w += (size_t)6 * ND * NDFF * 2;
  bf16_t* WoutT = (bf16_t*)w; w += (size_t)NV * ND * 2;
  if ((size_t)(w - (char*)d_ws) > ws_size) return;

  const int M = MROWS;
  const size_t U = (size_t)M * ND;         // elements per split-K half
  float* tmp1 = tmp + U;

  prep_kernel<<<10656, 256, 0, stream>>>(tokens, tok_emb, Wq, Wk, Wv, Wo, W1, W2, Wout,
                                         WqkvT, WoT, W1T, W2T, WoutT, x, xb);

  const dim3 gQKV(M / 64, QKVLD / 64);     // (32, 24) = 768 blocks
  const dim3 gFF1(M / 64, NDFF / 64);      // (32, 32) = 1024 blocks
  const dim3 gOut(M / 128, NV / 128);      // (16, 250)
  const dim3 g64s(M / 64, ND / 64, 2);     // (32, 8, 2) = 512 blocks, split-K
  const dim3 gAttn(16, NH, NB * 2);        // (16, 8, 4) = 512 blocks, t-half split

  const int ALLK = 0x7fffffff;

  for (int l = 0; l < NL; ++l) {
    gemm_qkv64<<<gQKV, 256, 0, stream>>>(xb, WqkvT + (size_t)l * QKVLD * ND,
        bq + l * ND, bk + l * ND, bv + l * ND, qkv, ND, ND, QKVLD);

    float* probs_l = attn_all + (size_t)l * NB * NH * NS * NS;
    attn_stats<<<gAttn, 256, 0, stream>>>(qkv, marr, sarr, probs_l);
    attn_pv<<<gAttn, 256, 0, stream>>>(qkv, marr, sarr, probs_l, ctxcat);

    // Wo: K=1024 over ctxcat halves, W col index mod 512 (kmask)
    gemm64<0, 0><<<g64s, 256, 0, stream>>>(ctxcat, WoT + (size_t)l * ND * ND,
        bo + l * ND, tmp, 1024, 1024, ND, 511, ND, U);
    add_ln_kernel<<<M, 256, 0, stream>>>(x, tmp, tmp1,
        ln1_g + l * ND, ln1_b + l * ND, nullptr, nullptr, xb);

    gemm64<1, 1><<<gFF1, 256, 0, stream>>>(xb, W1T + (size_t)l * NDFF * ND,
        b1 + l * NDFF, hh, ND, ND, ND, ALLK, NDFF, 0);
    gemm64<0, 0><<<g64s, 256, 0, stream>>>(hh, W2T + (size_t)l * ND * NDFF,
        b2 + l * ND, tmp, NDFF, NDFF, NDFF, ALLK, ND, U);
    // last layer: fuse the final lnf into this LN
    add_ln_kernel<<<M, 256, 0, stream>>>(x, tmp, tmp1,
        ln2_g + l * ND, ln2_b + l * ND,
        (l == NL - 1) ? lnf_g : nullptr, (l == NL - 1) ? lnf_b : nullptr, xb);
  }

  gemm_bt<0, 0><<<gOut, 256, 0, stream>>>(xb, WoutT, bout,
      logits, NV, ND, ND, NV);
}

// Round 17
// 639.856 us; speedup vs baseline: 1.0552x; 1.0283x over previous
//
#include <hip/hip_runtime.h>
#include <math.h>

#define NB 2
#define NS 1024
#define NH 8
#define NDK 64
#define ND 512
#define NDFF 2048
#define NV 32000
#define NL 6
#define MROWS (NB * NS)
#define QKVLD (3 * ND)   // 1536

using bf16_t = __bf16;
using bf16x4 = __attribute__((ext_vector_type(4))) __bf16;
using bf16x8 = __attribute__((ext_vector_type(8))) __bf16;
using f32x4  = __attribute__((ext_vector_type(4))) float;

__device__ __forceinline__ void gload_lds16(const bf16_t* g, bf16_t* l) {
  __builtin_amdgcn_global_load_lds(
      (const __attribute__((address_space(1))) void*)g,
      (__attribute__((address_space(3))) void*)l, 16, 0, 0);
}

__device__ __forceinline__ float gelu_exact(float v) {
  return 0.5f * v * (1.0f + erff(v * 0.7071067811865476f));
}

// ---------------------------------------------------------------- prep: all weight transposes + embed
__global__ __launch_bounds__(256)
void prep_kernel(const int* __restrict__ tokens, const float* __restrict__ emb,
                 const float* __restrict__ Wq, const float* __restrict__ Wk,
                 const float* __restrict__ Wv, const float* __restrict__ Wo,
                 const float* __restrict__ W1, const float* __restrict__ W2,
                 const float* __restrict__ Wout,
                 bf16_t* __restrict__ WqkvT, bf16_t* __restrict__ WoT,
                 bf16_t* __restrict__ W1T, bf16_t* __restrict__ W2T,
                 bf16_t* __restrict__ WoutT,
                 float* __restrict__ x, bf16_t* __restrict__ xb) {
  __shared__ bf16_t T[64][72];
  const int id = blockIdx.x;
  const int tid = threadIdx.x;

  if (id >= 8608) {                       // ---- embed
    const int row = id - 8608;            // b*NS + s
    const int s = row & (NS - 1);
    const int tok = tokens[row];
    const float SQRTD = 22.627416997969522f;
    const float C = -9.210340371976184f / (float)ND;
#pragma unroll
    for (int i = 0; i < 2; ++i) {
      const int d = tid + i * 256;
      const int pair = d >> 1;
      const float div = expf((float)(2 * pair) * C);
      const float ang = (float)s * div;
      const float pe = (d & 1) ? cosf(ang) : sinf(ang);
      const float v = emb[(size_t)tok * ND + d] * SQRTD + pe;
      x[(size_t)row * ND + d] = v;
      xb[(size_t)row * ND + d] = (bf16_t)v;
    }
    return;
  }

  const float* src; bf16_t* dst; int K, N, n0, k0;
  if (id < 1536) {                        // Wq/Wk/Wv/Wo, 512x512 each
    const int z = id >> 6, t = id & 63;
    const int mat = z / 6, layer = z % 6;
    src = ((mat == 0) ? Wq : (mat == 1) ? Wk : (mat == 2) ? Wv : Wo) + (size_t)layer * ND * ND;
    dst = (mat < 3) ? (WqkvT + (size_t)layer * QKVLD * ND + (size_t)mat * ND * ND)
                    : (WoT + (size_t)layer * ND * ND);
    K = ND; N = ND; n0 = (t & 7) * 64; k0 = (t >> 3) * 64;
  } else if (id < 3072) {                 // W1: [512][2048]
    const int idx = id - 1536, layer = idx >> 8, t = idx & 255;
    src = W1 + (size_t)layer * ND * NDFF; dst = W1T + (size_t)layer * NDFF * ND;
    K = ND; N = NDFF; n0 = (t & 31) * 64; k0 = (t >> 5) * 64;
  } else if (id < 4608) {                 // W2: [2048][512]
    const int idx = id - 3072, layer = idx >> 8, t = idx & 255;
    src = W2 + (size_t)layer * NDFF * ND; dst = W2T + (size_t)layer * ND * NDFF;
    K = NDFF; N = ND; n0 = (t & 7) * 64; k0 = (t >> 3) * 64;
  } else {                                // Wout: [512][32000]
    const int t = id - 4608;
    src = Wout; dst = WoutT;
    K = ND; N = NV; n0 = (t % 500) * 64; k0 = (t / 500) * 64;
  }

#pragma unroll
  for (int it = 0; it < 4; ++it) {
    const int k = (tid >> 4) + it * 16;
    const int c = (tid & 15) * 4;
    const f32x4 v = __builtin_nontemporal_load(
        (const f32x4*)&src[(size_t)(k0 + k) * N + n0 + c]);   // read-once: keep caches clean
    T[c + 0][k] = (bf16_t)v[0];
    T[c + 1][k] = (bf16_t)v[1];
    T[c + 2][k] = (bf16_t)v[2];
    T[c + 3][k] = (bf16_t)v[3];
  }
  __syncthreads();
  const int n = tid >> 2, kk = (tid & 3) * 16;
  bf16x8 a = *(const bf16x8*)&T[n][kk];
  bf16x8 b2v = *(const bf16x8*)&T[n][kk + 8];
  *(bf16x8*)&dst[(size_t)(n0 + n) * K + k0 + kk] = a;
  *(bf16x8*)&dst[(size_t)(n0 + n) * K + k0 + kk + 8] = b2v;
}

// ---------------------------------------------------------------- residual add (two partials) + LayerNorm (+ optional second LN)
__global__ __launch_bounds__(256)
void add_ln_kernel(float* __restrict__ x, const float* __restrict__ y0,
                   const float* __restrict__ y1,
                   const float* __restrict__ g, const float* __restrict__ bb,
                   const float* __restrict__ g2, const float* __restrict__ bb2,
                   bf16_t* __restrict__ xb) {
  const int row = blockIdx.x, tid = threadIdx.x;
  const size_t base = (size_t)row * ND;
  float v0 = x[base + tid], v1 = x[base + tid + 256];
  if (y0) { v0 += y0[base + tid]; v1 += y0[base + tid + 256]; }
  if (y1) { v0 += y1[base + tid]; v1 += y1[base + tid + 256]; }
  __shared__ float red[256];
  red[tid] = v0 + v1; __syncthreads();
  for (int o = 128; o > 0; o >>= 1) {
    if (tid < o) red[tid] += red[tid + o];
    __syncthreads();
  }
  const float mean = red[0] * (1.f / (float)ND);
  __syncthreads();
  const float d0 = v0 - mean, d1 = v1 - mean;
  red[tid] = d0 * d0 + d1 * d1; __syncthreads();
  for (int o = 128; o > 0; o >>= 1) {
    if (tid < o) red[tid] += red[tid + o];
    __syncthreads();
  }
  const float inv = 1.f / sqrtf(red[0] * (1.f / (float)ND) + 1e-5f);
  float o0 = d0 * inv * g[tid]       + bb[tid];
  float o1 = d1 * inv * g[tid + 256] + bb[tid + 256];

  if (g2) {       // fused second LayerNorm (final lnf)
    __syncthreads();
    red[tid] = o0 + o1; __syncthreads();
    for (int o = 128; o > 0; o >>= 1) {
      if (tid < o) red[tid] += red[tid + o];
      __syncthreads();
    }
    const float mean2 = red[0] * (1.f / (float)ND);
    __syncthreads();
    const float e0 = o0 - mean2, e1 = o1 - mean2;
    red[tid] = e0 * e0 + e1 * e1; __syncthreads();
    for (int o = 128; o > 0; o >>= 1) {
      if (tid < o) red[tid] += red[tid + o];
      __syncthreads();
    }
    const float inv2 = 1.f / sqrtf(red[0] * (1.f / (float)ND) + 1e-5f);
    o0 = e0 * inv2 * g2[tid]       + bb2[tid];
    o1 = e1 * inv2 * g2[tid + 256] + bb2[tid + 256];
  } else {
    x[base + tid] = o0;
    x[base + tid + 256] = o1;
  }
  xb[base + tid] = (bf16_t)o0; xb[base + tid + 256] = (bf16_t)o1;
}

// ---------------------------------------------------------------- 128x128 GEMM, BK=64 (logits), XCD swizzle
template <int ACT, int OUTBF>
__global__ __launch_bounds__(256)
void gemm_bt(const bf16_t* __restrict__ A, const bf16_t* __restrict__ Wt,
             const float* __restrict__ B0,
             void* __restrict__ Cout, int N, int K, int lda, int ldc) {
  __shared__ bf16_t As[128 * 64];
  __shared__ bf16_t Bs[128 * 64];
  const int tid = threadIdx.x, lane = tid & 63, w = tid >> 6;
  const int wm = w >> 1, wn = w & 1;
  const int lcol = lane & 15, hi = lane >> 4;

  // bijective XCD swizzle (m204)
  const int nwg = gridDim.x * gridDim.y;
  const int flat = blockIdx.y * gridDim.x + blockIdx.x;
  const int q = nwg >> 3, r = nwg & 7;
  const int xcd = flat & 7, idx = flat >> 3;
  const int nf = (xcd < r ? xcd * (q + 1) : r * (q + 1) + (xcd - r) * q) + idx;
  const int m0 = (nf % gridDim.x) * 128, n0 = (nf / gridDim.x) * 128;

  const int sr8 = lane >> 3;        // 0..7
  const int sslot = lane & 7;       // 16B slot 0..7

  f32x4 acc[4][4] = {};

  for (int k0 = 0; k0 < K; k0 += 64) {
#pragma unroll
    for (int t = 0; t < 2; ++t) {
#pragma unroll
      for (int c = 0; c < 2; ++c) {
        const int rbase = t * 64 + w * 16 + c * 8;     // wave-uniform
        const int row = rbase + sr8;
        const int ks = sslot ^ (row & 7);
        gload_lds16(&A[(size_t)(m0 + row) * lda + k0 + ks * 8], &As[rbase * 64]);
        gload_lds16(&Wt[(size_t)(n0 + row) * K + k0 + ks * 8], &Bs[rbase * 64]);
      }
    }
    __syncthreads();

#pragma unroll
    for (int kk = 0; kk < 2; ++kk) {
      bf16x8 af[4], bf[4];
#pragma unroll
      for (int m = 0; m < 4; ++m) {
        const int rr = wm * 64 + m * 16 + lcol;
        af[m] = *(const bf16x8*)&As[rr * 64 + (((kk * 4 + hi) ^ (rr & 7)) * 8)];
      }
#pragma unroll
      for (int n = 0; n < 4; ++n) {
        const int rr = wn * 64 + n * 16 + lcol;
        bf[n] = *(const bf16x8*)&Bs[rr * 64 + (((kk * 4 + hi) ^ (rr & 7)) * 8)];
      }
#pragma unroll
      for (int m = 0; m < 4; ++m)
#pragma unroll
        for (int n = 0; n < 4; ++n)
          acc[m][n] = __builtin_amdgcn_mfma_f32_16x16x32_bf16(bf[n], af[m], acc[m][n], 0, 0, 0);
    }
    __syncthreads();
  }

#pragma unroll
  for (int m = 0; m < 4; ++m) {
    const int row = m0 + wm * 64 + m * 16 + lcol;
#pragma unroll
    for (int n = 0; n < 4; ++n) {
      const int col = n0 + wn * 64 + n * 16 + hi * 4;
      const f32x4 bv = *(const f32x4*)&B0[col];
      f32x4 v;
#pragma unroll
      for (int i = 0; i < 4; ++i) {
        float t = acc[m][n][i] + bv[i];
        if (ACT == 1) t = gelu_exact(t);
        v[i] = t;
      }
      if (OUTBF) {
        bf16x4 o;
#pragma unroll
        for (int i = 0; i < 4; ++i) o[i] = (bf16_t)v[i];
        *(bf16x4*)&((bf16_t*)Cout)[(size_t)row * ldc + col] = o;
      } else {
        __builtin_nontemporal_store(v, (f32x4*)&((float*)Cout)[(size_t)row * ldc + col]);
      }
    }
  }
}

// ---------------------------------------------------------------- 64x64 GEMM, BK=128, 3-way bias (QKV), bf16 out
__global__ __launch_bounds__(256)
void gemm_qkv64(const bf16_t* __restrict__ A, const bf16_t* __restrict__ Wt,
                const float* __restrict__ B0, const float* __restrict__ B1,
                const float* __restrict__ B2,
                bf16_t* __restrict__ Cout, int K, int lda, int ldc) {
  __shared__ bf16_t As[64 * 128];   // 16KB each, row stride 256B, 16 slots
  __shared__ bf16_t Bs[64 * 128];
  const int tid = threadIdx.x, lane = tid & 63, w = tid >> 6;
  const int wm = w >> 1, wn = w & 1;
  const int lcol = lane & 15, hi = lane >> 4;
  const int m0 = blockIdx.x * 64, n0 = blockIdx.y * 64;
  const int sr4 = lane >> 4, sslot = lane & 15;

  f32x4 acc[2][2] = {};

  for (int k0 = 0; k0 < K; k0 += 128) {
#pragma unroll
    for (int c = 0; c < 4; ++c) {
      const int rbase = w * 16 + c * 4;                // wave-uniform
      const int row = rbase + sr4;
      const int ks = sslot ^ (row & 15);
      gload_lds16(&A[(size_t)(m0 + row) * lda + k0 + ks * 8], &As[rbase * 128]);
      gload_lds16(&Wt[(size_t)(n0 + row) * K + k0 + ks * 8], &Bs[rbase * 128]);
    }
    __syncthreads();

#pragma unroll
    for (int kk = 0; kk < 4; ++kk) {
      bf16x8 af[2], bf[2];
#pragma unroll
      for (int m = 0; m < 2; ++m) {
        const int rr = wm * 32 + m * 16 + lcol;
        af[m] = *(const bf16x8*)&As[rr * 128 + (((kk * 4 + hi) ^ (rr & 15)) * 8)];
      }
#pragma unroll
      for (int n = 0; n < 2; ++n) {
        const int rr = wn * 32 + n * 16 + lcol;
        bf[n] = *(const bf16x8*)&Bs[rr * 128 + (((kk * 4 + hi) ^ (rr & 15)) * 8)];
      }
#pragma unroll
      for (int m = 0; m < 2; ++m)
#pragma unroll
        for (int n = 0; n < 2; ++n)
          acc[m][n] = __builtin_amdgcn_mfma_f32_16x16x32_bf16(bf[n], af[m], acc[m][n], 0, 0, 0);
    }
    __syncthreads();
  }

#pragma unroll
  for (int m = 0; m < 2; ++m) {
    const int row = m0 + wm * 32 + m * 16 + lcol;
#pragma unroll
    for (int n = 0; n < 2; ++n) {
      const int col = n0 + wn * 32 + n * 16 + hi * 4;
      const int sel = col >> 9;
      const float* Bp = (sel == 0) ? B0 : (sel == 1) ? B1 : B2;
      const f32x4 bv = *(const f32x4*)&Bp[col & 511];
      bf16x4 o;
#pragma unroll
      for (int i = 0; i < 4; ++i) o[i] = (bf16_t)(acc[m][n][i] + bv[i]);
      *(bf16x4*)&Cout[(size_t)row * ldc + col] = o;
    }
  }
}

// ---------------------------------------------------------------- 64x64 GEMM, BK=128, single bias, optional split-K
// Wt col index = (k & kmask) so a wide-K A (concatenated partials) can share one [N][512] W.
template <int ACT, int OUTBF>
__global__ __launch_bounds__(256)
void gemm64(const bf16_t* __restrict__ A, const bf16_t* __restrict__ Wt,
            const float* __restrict__ bias,
            void* __restrict__ Cout, int K, int lda, int ldw, int kmask,
            int ldc, size_t zstride) {
  __shared__ bf16_t As[64 * 128];
  __shared__ bf16_t Bs[64 * 128];
  const int tid = threadIdx.x, lane = tid & 63, w = tid >> 6;
  const int wm = w >> 1, wn = w & 1;
  const int lcol = lane & 15, hi = lane >> 4;
  const int m0 = blockIdx.x * 64, n0 = blockIdx.y * 64;
  const int sr4 = lane >> 4, sslot = lane & 15;
  const int kc = K / gridDim.z;
  const int kbeg = blockIdx.z * kc;

  f32x4 acc[2][2] = {};

  for (int k0 = kbeg; k0 < kbeg + kc; k0 += 128) {
#pragma unroll
    for (int c = 0; c < 4; ++c) {
      const int rbase = w * 16 + c * 4;
      const int row = rbase + sr4;
      const int ks = sslot ^ (row & 15);
      gload_lds16(&A[(size_t)(m0 + row) * lda + k0 + ks * 8], &As[rbase * 128]);
      gload_lds16(&Wt[(size_t)(n0 + row) * ldw + ((k0 & kmask) + ks * 8)], &Bs[rbase * 128]);
    }
    __syncthreads();

#pragma unroll
    for (int kk = 0; kk < 4; ++kk) {
      bf16x8 af[2], bf[2];
#pragma unroll
      for (int m = 0; m < 2; ++m) {
        const int rr = wm * 32 + m * 16 + lcol;
        af[m] = *(const bf16x8*)&As[rr * 128 + (((kk * 4 + hi) ^ (rr & 15)) * 8)];
      }
#pragma unroll
      for (int n = 0; n < 2; ++n) {
        const int rr = wn * 32 + n * 16 + lcol;
        bf[n] = *(const bf16x8*)&Bs[rr * 128 + (((kk * 4 + hi) ^ (rr & 15)) * 8)];
      }
#pragma unroll
      for (int m = 0; m < 2; ++m)
#pragma unroll
        for (int n = 0; n < 2; ++n)
          acc[m][n] = __builtin_amdgcn_mfma_f32_16x16x32_bf16(bf[n], af[m], acc[m][n], 0, 0, 0);
    }
    __syncthreads();
  }

#pragma unroll
  for (int m = 0; m < 2; ++m) {
    const int row = m0 + wm * 32 + m * 16 + lcol;
#pragma unroll
    for (int n = 0; n < 2; ++n) {
      const int col = n0 + wn * 32 + n * 16 + hi * 4;
      f32x4 bv = {0.f, 0.f, 0.f, 0.f};
      if (blockIdx.z == 0) bv = *(const f32x4*)&bias[col];
      f32x4 v;
#pragma unroll
      for (int i = 0; i < 4; ++i) {
        float t = acc[m][n][i] + bv[i];
        if (ACT == 1) t = gelu_exact(t);
        v[i] = t;
      }
      if (OUTBF) {
        bf16x4 o;
#pragma unroll
        for (int i = 0; i < 4; ++i) o[i] = (bf16_t)v[i];
        *(bf16x4*)&((bf16_t*)Cout)[(size_t)row * ldc + col] = o;
      } else {
        *(f32x4*)&((float*)Cout)[blockIdx.z * zstride + (size_t)row * ldc + col] = v;
      }
    }
  }
}

// ---------------------------------------------------------------- attention stats: partial (m,s) per t-half
// grid (16, NH, NB*2); z -> b = z>>1, half = z&1. Tiles tt = half, half+2, ...
__global__ __launch_bounds__(256)
void attn_stats(const bf16_t* __restrict__ qkv,
                float* __restrict__ marr, float* __restrict__ sarr) {
  const int qt = 15 - blockIdx.x;            // heavy blocks first
  const int h = blockIdx.y;
  const int b = blockIdx.z >> 1, half = blockIdx.z & 1;
  const int q0 = qt * 64;
  const int NTT = (q0 >> 7) + 1;
  const int qmax = q0 + 63;
  const int tid = threadIdx.x, lane = tid & 63, wq = tid >> 6;
  const int lcol = lane & 15, hi = lane >> 4;

  __shared__ bf16_t Qs[64][72];
  __shared__ bf16_t Ks[128][72];

  {
    const int r = tid >> 2, c = (tid & 3) * 16;
    const bf16_t* src = &qkv[((size_t)(b * NS + q0 + r)) * QKVLD + h * NDK + c];
    *(bf16x8*)&Qs[r][c]     = *(const bf16x8*)&src[0];
    *(bf16x8*)&Qs[r][c + 8] = *(const bf16x8*)&src[8];
  }
  __syncthreads();
  const bf16x8 qf0 = *(const bf16x8*)&Qs[wq * 16 + lcol][hi * 8];
  const bf16x8 qf1 = *(const bf16x8*)&Qs[wq * 16 + lcol][32 + hi * 8];
  const int qrow = q0 + wq * 16 + lcol;
  const float scale = 0.125f;

  float m_run = -1e30f, s_run = 0.f;

  for (int tt = half; tt < NTT; tt += 2) {
    const int t0 = tt * 128;
    const int fmax = min(8, ((qmax - t0) >> 4) + 1);
    {
      const int r = tid >> 1, cb = (tid & 1) * 32;
      const bf16_t* src = &qkv[((size_t)(b * NS + t0 + r)) * QKVLD + ND + h * NDK + cb];
#pragma unroll
      for (int j = 0; j < 4; ++j)
        *(bf16x8*)&Ks[r][cb + j * 8] = *(const bf16x8*)&src[j * 8];
    }
    __syncthreads();

    float tmax = -1e30f;
    f32x4 sc[8];
#pragma unroll
    for (int f = 0; f < 8; ++f) {
      if (f >= fmax) break;
      f32x4 s4 = {};
      const bf16x8 ka0 = *(const bf16x8*)&Ks[f * 16 + lcol][hi * 8];
      const bf16x8 ka1 = *(const bf16x8*)&Ks[f * 16 + lcol][32 + hi * 8];
      s4 = __builtin_amdgcn_mfma_f32_16x16x32_bf16(ka0, qf0, s4, 0, 0, 0);
      s4 = __builtin_amdgcn_mfma_f32_16x16x32_bf16(ka1, qf1, s4, 0, 0, 0);
#pragma unroll
      for (int i = 0; i < 4; ++i) {
        const int t = t0 + f * 16 + hi * 4 + i;
        const float v = (t <= qrow) ? s4[i] * scale : -1e30f;
        s4[i] = v;
        tmax = fmaxf(tmax, v);
      }
      sc[f] = s4;
    }
    tmax = fmaxf(tmax, __shfl_xor(tmax, 16));
    tmax = fmaxf(tmax, __shfl_xor(tmax, 32));
    const float m_new = fmaxf(m_run, tmax);
    float sum = 0.f;
#pragma unroll
    for (int f = 0; f < 8; ++f) {
      if (f >= fmax) break;
#pragma unroll
      for (int i = 0; i < 4; ++i) sum += __expf(sc[f][i] - m_new);
    }
    sum += __shfl_xor(sum, 16);
    sum += __shfl_xor(sum, 32);
    s_run = s_run * __expf(m_run - m_new) + sum;
    m_run = m_new;
    __syncthreads();
  }

  if (hi == 0) {
    const size_t idx = (((size_t)half * NB + b) * NH + h) * NS + qrow;
    marr[idx] = m_run;
    sarr[idx] = s_run;
  }
}

// ---------------------------------------------------------------- attention probs+PV with merged stats, t-half split
// ctxcat: [M][1024] bf16, half h writes cols [h*512 + head*64 .. +64)
__global__ __launch_bounds__(256)
void attn_pv(const bf16_t* __restrict__ qkv,
             const float* __restrict__ marr, const float* __restrict__ sarr,
             float* __restrict__ probs, bf16_t* __restrict__ ctxcat) {
  const int qt = 15 - blockIdx.x;
  const int h = blockIdx.y;
  const int b = blockIdx.z >> 1, half = blockIdx.z & 1;
  const int q0 = qt * 64;
  const int NTT = (q0 >> 7) + 1;
  const int qmax = q0 + 63;
  const int tid = threadIdx.x, lane = tid & 63, wq = tid >> 6;
  const int lcol = lane & 15, hi = lane >> 4;

  __shared__ bf16_t Qs[64][72];
  __shared__ bf16_t Ks[128][72];
  __shared__ bf16_t Vs[64][132];
  __shared__ bf16_t Ps[64][132];

  // zero-fill probs for t >= NTT*128 (half 0 only)
  if (half == 0) {
    const int z0 = NTT * 128;
    const int nz = (NS - z0) >> 2;
    if (nz > 0) {
      const f32x4 zf = {0.f, 0.f, 0.f, 0.f};
      for (int idx = tid; idx < 64 * nz; idx += 256) {
        const int r = idx / nz, c = (idx - r * nz) * 4;
        __builtin_nontemporal_store(zf,
            (f32x4*)&probs[(((size_t)b * NH + h) * NS + q0 + r) * NS + z0 + c]);
      }
    }
  }

  {
    const int r = tid >> 2, c = (tid & 3) * 16;
    const bf16_t* src = &qkv[((size_t)(b * NS + q0 + r)) * QKVLD + h * NDK + c];
    *(bf16x8*)&Qs[r][c]     = *(const bf16x8*)&src[0];
    *(bf16x8*)&Qs[r][c + 8] = *(const bf16x8*)&src[8];
  }
  __syncthreads();
  const bf16x8 qf0 = *(const bf16x8*)&Qs[wq * 16 + lcol][hi * 8];
  const bf16x8 qf1 = *(const bf16x8*)&Qs[wq * 16 + lcol][32 + hi * 8];
  const int qrow = q0 + wq * 16 + lcol;
  const float scale = 0.125f;

  // merge the two partial stats
  const size_t i0 = (((size_t)0 * NB + b) * NH + h) * NS + qrow;
  const size_t i1 = (((size_t)1 * NB + b) * NH + h) * NS + qrow;
  const float m0 = marr[i0], m1 = marr[i1];
  const float s0 = sarr[i0], s1 = sarr[i1];
  const float m_fin = fmaxf(m0, m1);
  const float s_fin = s0 * __expf(m0 - m_fin) + s1 * __expf(m1 - m_fin);
  const float inv = 1.f / s_fin;

  f32x4 cacc[4] = {};
  const size_t prow = (((size_t)b * NH + h) * NS + qrow) * NS;
  for (int tt = half; tt < NTT; tt += 2) {
    const int t0 = tt * 128;
    const int fmax = min(8, ((qmax - t0) >> 4) + 1);
    {
      const int r = tid >> 1, cb = (tid & 1) * 32;
      const bf16_t* src = &qkv[((size_t)(b * NS + t0 + r)) * QKVLD + ND + h * NDK + cb];
#pragma unroll
      for (int j = 0; j < 4; ++j)
        *(bf16x8*)&Ks[r][cb + j * 8] = *(const bf16x8*)&src[j * 8];
    }
    {
      // V: register 4x4 transpose -> vectorized b64 LDS stores
#pragma unroll
      for (int it = 0; it < 2; ++it) {
        const int t4 = (tid >> 4) * 4 + it * 64;
        const int dk4 = (tid & 15) * 4;
        bf16x4 rr[4];
#pragma unroll
        for (int i = 0; i < 4; ++i)
          rr[i] = *(const bf16x4*)&qkv[((size_t)(b * NS + t0 + t4 + i)) * QKVLD + 2 * ND + h * NDK + dk4];
#pragma unroll
        for (int j = 0; j < 4; ++j) {
          bf16x4 c;
#pragma unroll
          for (int i = 0; i < 4; ++i) c[i] = rr[i][j];
          *(bf16x4*)&Vs[dk4 + j][t4] = c;
        }
      }
    }
    __syncthreads();

    const f32x4 zf = {0.f, 0.f, 0.f, 0.f};
    const bf16x4 zb = {(bf16_t)0.f, (bf16_t)0.f, (bf16_t)0.f, (bf16_t)0.f};
#pragma unroll
    for (int f = 0; f < 8; ++f) {
      if (f < fmax) {
        f32x4 s4 = {};
        const bf16x8 ka0 = *(const bf16x8*)&Ks[f * 16 + lcol][hi * 8];
        const bf16x8 ka1 = *(const bf16x8*)&Ks[f * 16 + lcol][32 + hi * 8];
        s4 = __builtin_amdgcn_mfma_f32_16x16x32_bf16(ka0, qf0, s4, 0, 0, 0);
        s4 = __builtin_amdgcn_mfma_f32_16x16x32_bf16(ka1, qf1, s4, 0, 0, 0);
        f32x4 pw;
        bf16x4 pb;
#pragma unroll
        for (int i = 0; i < 4; ++i) {
          const int t = t0 + f * 16 + hi * 4 + i;
          const float v = (t <= qrow) ? s4[i] * scale : -1e30f;
          const float pr = __expf(v - m_fin) * inv;
          pw[i] = pr;
          pb[i] = (bf16_t)pr;
        }
        __builtin_nontemporal_store(pw, (f32x4*)&probs[prow + t0 + f * 16 + hi * 4]);
        *(bf16x4*)&Ps[wq * 16 + lcol][f * 16 + hi * 4] = pb;
      } else {
        __builtin_nontemporal_store(zf, (f32x4*)&probs[prow + t0 + f * 16 + hi * 4]);
        *(bf16x4*)&Ps[wq * 16 + lcol][f * 16 + hi * 4] = zb;
      }
    }

#pragma unroll
    for (int ks = 0; ks < 4; ++ks) {
      const bf16x8 pf = *(const bf16x8*)&Ps[wq * 16 + lcol][ks * 32 + hi * 8];
#pragma unroll
      for (int df = 0; df < 4; ++df) {
        const bf16x8 vf = *(const bf16x8*)&Vs[df * 16 + lcol][ks * 32 + hi * 8];
        cacc[df] = __builtin_amdgcn_mfma_f32_16x16x32_bf16(vf, pf, cacc[df], 0, 0, 0);
      }
    }
    __syncthreads();
  }

#pragma unroll
  for (int df = 0; df < 4; ++df) {
    bf16x4 o;
#pragma unroll
    for (int i = 0; i < 4; ++i) o[i] = (bf16_t)cacc[df][i];
    *(bf16x4*)&ctxcat[((size_t)(b * NS + qrow)) * 1024 + half * 512 + h * NDK + df * 16 + hi * 4] = o;
  }
}

// ---------------------------------------------------------------- launch
extern "C" void kernel_launch(void* const* d_in, const int* in_sizes, int n_in,
                              void* d_out, int out_size, void* d_ws, size_t ws_size,
                              hipStream_t stream) {
  const int*   tokens  = (const int*)d_in[0];
  const float* tok_emb = (const float*)d_in[1];
  const float* Wq = (const float*)d_in[2];
  const float* bq = (const float*)d_in[3];
  const float* Wk = (const float*)d_in[4];
  const float* bk = (const float*)d_in[5];
  const float* Wv = (const float*)d_in[6];
  const float* bv = (const float*)d_in[7];
  const float* Wo = (const float*)d_in[8];
  const float* bo = (const float*)d_in[9];
  const float* ln1_g = (const float*)d_in[10];
  const float* ln1_b = (const float*)d_in[11];
  const float* W1 = (const float*)d_in[12];
  const float* b1 = (const float*)d_in[13];
  const float* W2 = (const float*)d_in[14];
  const float* b2 = (const float*)d_in[15];
  const float* ln2_g = (const float*)d_in[16];
  const float* ln2_b = (const float*)d_in[17];
  const float* lnf_g = (const float*)d_in[18];
  const float* lnf_b = (const float*)d_in[19];
  const float* Wout = (const float*)d_in[20];
  const float* bout = (const float*)d_in[21];

  float* logits   = (float*)d_out;                               // [B,S,V]
  float* attn_all = (float*)d_out + (size_t)NB * NS * NV;        // [L,B,H,S,S]

  char* w = (char*)d_ws;
  float* x    = (float*)w;  w += (size_t)4 << 20;
  float* tmp  = (float*)w;  w += (size_t)8 << 20;   // two 4MB split-K halves
  bf16_t* xb  = (bf16_t*)w; w += (size_t)2 << 20;
  bf16_t* qkv = (bf16_t*)w; w += (size_t)6 << 20;
  float* marr = (float*)w;                          // 128KB stats (2 halves)
  float* sarr = (float*)(w + (512 << 10));          // 128KB
  w += (size_t)2 << 20;
  bf16_t* hh  = (bf16_t*)w;                         // [M][2048] (FF1)
  bf16_t* ctxcat = (bf16_t*)w;                      // [M][1024] overlays hh (disjoint lifetime)
  w += (size_t)8 << 20;
  bf16_t* WqkvT = (bf16_t*)w; w += (size_t)6 * QKVLD * ND * 2;
  bf16_t* WoT   = (bf16_t*)w; w += (size_t)6 * ND * ND * 2;
  bf16_t* W1T   = (bf16_t*)w; w += (size_t)6 * NDFF * ND * 2;
  bf16_t* W2T   = (bf16_t*)w; w += (size_t)6 * ND * NDFF * 2;
  bf16_t* WoutT = (bf16_t*)w; w += (size_t)NV * ND * 2;
  if ((size_t)(w - (char*)d_ws) > ws_size) return;

  const int M = MROWS;
  const size_t U = (size_t)M * ND;         // elements per split-K half
  float* tmp1 = tmp + U;

  prep_kernel<<<10656, 256, 0, stream>>>(tokens, tok_emb, Wq, Wk, Wv, Wo, W1, W2, Wout,
                                         WqkvT, WoT, W1T, W2T, WoutT, x, xb);

  const dim3 gQKV(M / 64, QKVLD / 64);     // (32, 24) = 768 blocks
  const dim3 gFF1(M / 64, NDFF / 64);      // (32, 32) = 1024 blocks
  const dim3 gOut(M / 128, NV / 128);      // (16, 250)
  const dim3 g64s(M / 64, ND / 64, 2);     // (32, 8, 2) = 512 blocks, split-K
  const dim3 gAttn(16, NH, NB * 2);        // (16, 8, 4) = 512 blocks, t-half split

  const int ALLK = 0x7fffffff;

  for (int l = 0; l < NL; ++l) {
    gemm_qkv64<<<gQKV, 256, 0, stream>>>(xb, WqkvT + (size_t)l * QKVLD * ND,
        bq + l * ND, bk + l * ND, bv + l * ND, qkv, ND, ND, QKVLD);

    float* probs_l = attn_all + (size_t)l * NB * NH * NS * NS;
    attn_stats<<<gAttn, 256, 0, stream>>>(qkv, marr, sarr);
    attn_pv<<<gAttn, 256, 0, stream>>>(qkv, marr, sarr, probs_l, ctxcat);

    // Wo: K=1024 over ctxcat halves, W col index mod 512 (kmask)
    gemm64<0, 0><<<g64s, 256, 0, stream>>>(ctxcat, WoT + (size_t)l * ND * ND,
        bo + l * ND, tmp, 1024, 1024, ND, 511, ND, U);
    add_ln_kernel<<<M, 256, 0, stream>>>(x, tmp, tmp1,
        ln1_g + l * ND, ln1_b + l * ND, nullptr, nullptr, xb);

    gemm64<1, 1><<<gFF1, 256, 0, stream>>>(xb, W1T + (size_t)l * NDFF * ND,
        b1 + l * NDFF, hh, ND, ND, ND, ALLK, NDFF, 0);
    gemm64<0, 0><<<g64s, 256, 0, stream>>>(hh, W2T + (size_t)l * ND * NDFF,
        b2 + l * ND, tmp, NDFF, NDFF, NDFF, ALLK, ND, U);
    // last layer: fuse the final lnf into this LN
    add_ln_kernel<<<M, 256, 0, stream>>>(x, tmp, tmp1,
        ln2_g + l * ND, ln2_b + l * ND,
        (l == NL - 1) ? lnf_g : nullptr, (l == NL - 1) ? lnf_b : nullptr, xb);
  }

  gemm_bt<0, 0><<<gOut, 256, 0, stream>>>(xb, WoutT, bout,
      logits, NV, ND, ND, NV);
}